// Round 4
// baseline (327.288 us; speedup 1.0000x reference)
//
#include <hip/hip_runtime.h>
#include <hip/hip_bf16.h>
#include <stdint.h>

typedef __bf16 bf16;
typedef __attribute__((ext_vector_type(8))) __bf16 bf16x8;
typedef __attribute__((ext_vector_type(4))) float f32x4;
typedef __attribute__((ext_vector_type(4))) unsigned int u32x4;

#define NH 16
#define DH 64
#define POOL 8
#define BATCH 4
#define SEQ 4096
#define DIMV 1024
#define QKV_N (3*DIMV)
#define M_TOTAL (BATCH*SEQ)
#define SCALE_F 0.125f
// agent buffer holds SUMS over 512 t (from GEMM1-epilogue atomics);
// consumers fold mean (1/512) into the pre-softmax dot: exact.
#define AGS_F (SCALE_F / 512.0f)
#define BH (BATCH*NH)              // 64
#define QKVSZ ((size_t)BH*SEQ*DH)  // elems per q/k/v plane
#define TCH 16                     // t-split chunks for stage1
#define TCL (SEQ/TCH)              // 256 t per chunk
#define HP 128                     // h*p combined dim for P2/W2

#define AS1(p) ((const __attribute__((address_space(1))) void*)(p))
#define AS3(p) ((__attribute__((address_space(3))) void*)(p))
typedef const __attribute__((address_space(3))) char* lds_cp;

// ---------------- elementwise fp32 -> bf16 (8 elems/thread) ----------------
__global__ void convert_x(const float* __restrict__ in, bf16* __restrict__ out) {
  size_t i = ((size_t)blockIdx.x * 256 + threadIdx.x) * 8;
  float4 f0 = *(const float4*)(in + i);
  float4 f1 = *(const float4*)(in + i + 4);
  bf16x8 o;
  o[0] = (bf16)f0.x; o[1] = (bf16)f0.y; o[2] = (bf16)f0.z; o[3] = (bf16)f0.w;
  o[4] = (bf16)f1.x; o[5] = (bf16)f1.y; o[6] = (bf16)f1.z; o[7] = (bf16)f1.w;
  *(bf16x8*)(out + i) = o;
}

// ---------------- transpose fp32 [R][C] -> bf16 [C][R] ----------------
__global__ void transpose_f32_bf16(const float* __restrict__ in, bf16* __restrict__ out,
                                   int R, int C) {
  __shared__ float tile[32][33];
  int c0 = blockIdx.x * 32, r0 = blockIdx.y * 32;
  int tx = threadIdx.x & 31, ty = threadIdx.x >> 5;
  for (int i = ty; i < 32; i += 8)
    tile[i][tx] = in[(size_t)(r0 + i) * C + c0 + tx];
  __syncthreads();
  for (int i = ty; i < 32; i += 8)
    out[(size_t)(c0 + i) * R + r0 + tx] = (bf16)tile[tx][i];
}

// ============================================================================
// GEMM1: 256x256 tile, BK=64, 8 waves.  R3: counted-lgkm pipeline, race-fixed.
//   R2 bug: mid-tile ISSUE of next tile's B01 overwrote bR[0..1] while G3
//   (quadrant 1,0) still needed them -> register WAR race.  R3: mid-tile
//   issues ONLY A-qm0(t+1) (consumed by G1/G2 only); B01/B23/A-qm1(t+1)
//   issue at end-of-tile after G3/G4 consumed their registers.
//   In-order DS retirement sequence per tile: [Aqm0(8) | B01(4) B23(4)
//   Aqm1(8)], so counted waits are: top lgkm(12) -> G1; lgkm(8) -> G2;
//   mid vmcnt(0)+BAR, issue Aqm0(nxt), lgkm(8) -> G3 (old Aqm1 retired,
//   the 8 newest outstanding are the new Aqm0); end BAR, issue REST+STAGE.
// 2 barriers + 1 vmcnt(0) per tile; swizzle/addressing identical to R1
// (verified: bank conflicts = 0).  rule #18: sched_barrier(0) after waits.
// ============================================================================
__global__ __launch_bounds__(512, 2)
void gemm1_qkv(const bf16* __restrict__ A, const bf16* __restrict__ B,
               bf16* __restrict__ qkvOut, float* __restrict__ agentSum) {
  constexpr int K1 = DIMV;     // 1024
  constexpr int NT = K1 / 64;  // 16 K-tiles

  __shared__ __align__(16) bf16 LA[2][2][8192];   // [buf][half][128*64]
  __shared__ __align__(16) bf16 LB[2][2][8192];

  const int tid  = threadIdx.x;
  const int w    = tid >> 6;
  const int lane = tid & 63;
  const int wm = (w >> 2) * 128;         // 2 M-waves x 4 N-waves
  const int wn = (w & 3) * 64;

  // bijective XCD swizzle (768 % 8 == 0)
  const int bid = blockIdx.x;
  const int swz = (bid & 7) * 96 + (bid >> 3);
  const int m0 = (swz / 12) * 256;
  const int n0 = (swz % 12) * 256;

  // staging: thread t covers (row rT + 64*e + 128*half, 16B slot t&7);
  // source column pre-swizzled so linear LDS dest realizes slot^(row&7).
  const int rT  = tid >> 3;
  const int csT = (((tid & 7) ^ (rT & 7)) << 3);
  const bf16* Ag = A + (size_t)(m0 + rT) * K1 + csT;
  const bf16* Bg = B + (size_t)(n0 + rT) * K1 + csT;

  // ds_read lane constants
  const int rA = lane & 15, C = lane >> 4, xr = rA & 7;
  const unsigned s0 = (unsigned)(((0 * 4 + C) ^ xr) << 4);   // ks=0 slot byte
  const unsigned s1 = (unsigned)(((1 * 4 + C) ^ xr) << 4);   // ks=1 slot byte
  const unsigned aoff = (unsigned)((wm + rA) << 7);
  const unsigned boff = (unsigned)((wn + rA) << 7);

  f32x4 acc[8][4] = {};
  u32x4 aR[4][2], aR2[4][2], bR[4][2];

#define STG(arr, Gp, half, kofs) do {                                         \
    const bf16* _s = (Gp) + (size_t)((half) * 128) * K1 + (kofs);             \
    char* _d = (char*)&arr[half][0] + (w << 10);                              \
    __builtin_amdgcn_global_load_lds(AS1(_s), AS3(_d), 16, 0, 0);             \
    __builtin_amdgcn_global_load_lds(AS1(_s + 64 * K1), AS3(_d + 8192), 16, 0, 0); \
  } while (0)

#define STAGE(tt, bb) do { const int _k = (tt) * 64;                          \
    STG(LA[bb], Ag, 0, _k); STG(LA[bb], Ag, 1, _k);                           \
    STG(LB[bb], Bg, 0, _k); STG(LB[bb], Bg, 1, _k); } while (0)

#define DSR0(d, p)    asm volatile("ds_read_b128 %0, %1" : "=v"(d) : "v"(p))
#define DSR(d, p, o)  asm volatile("ds_read_b128 %0, %1 offset:" o : "=v"(d) : "v"(p))

// A-qm0: 8 reads -> aR (rows wm..wm+63).  Issued at MID of previous tile;
// only overwrites registers consumed by G1/G2.
#define ISSUE_A0(bb) do {                                                     \
    lds_cp _pa0 = (lds_cp)(const char*)&LA[bb][0][0] + aoff + s0;             \
    lds_cp _pa1 = (lds_cp)(const char*)&LA[bb][0][0] + aoff + s1;             \
    DSR0(aR[0][0], _pa0); DSR(aR[1][0], _pa0, "2048");                        \
    DSR(aR[2][0], _pa0, "4096"); DSR(aR[3][0], _pa0, "6144");                 \
    DSR0(aR[0][1], _pa1); DSR(aR[1][1], _pa1, "2048");                        \
    DSR(aR[2][1], _pa1, "4096"); DSR(aR[3][1], _pa1, "6144");                 \
  } while (0)

// REST: B01 (4 reads), B23 (4 reads), A-qm1 (8 reads) -- this issue order is
// what the counted lgkm waits index into.  Issued at END of previous tile,
// after G3/G4 consumed bR/aR2.
#define ISSUE_REST(bb) do {                                                   \
    lds_cp _pb0 = (lds_cp)(const char*)&LB[bb][0][0] + boff + s0;             \
    lds_cp _pb1 = (lds_cp)(const char*)&LB[bb][0][0] + boff + s1;             \
    DSR0(bR[0][0], _pb0); DSR(bR[1][0], _pb0, "2048");                        \
    DSR0(bR[0][1], _pb1); DSR(bR[1][1], _pb1, "2048");                        \
    DSR(bR[2][0], _pb0, "4096"); DSR(bR[3][0], _pb0, "6144");                 \
    DSR(bR[2][1], _pb1, "4096"); DSR(bR[3][1], _pb1, "6144");                 \
    lds_cp _pa0 = (lds_cp)(const char*)&LA[bb][0][0] + aoff + s0 + 8192;      \
    lds_cp _pa1 = (lds_cp)(const char*)&LA[bb][0][0] + aoff + s1 + 8192;      \
    DSR0(aR2[0][0], _pa0); DSR(aR2[1][0], _pa0, "2048");                      \
    DSR(aR2[2][0], _pa0, "4096"); DSR(aR2[3][0], _pa0, "6144");               \
    DSR0(aR2[0][1], _pa1); DSR(aR2[1][1], _pa1, "2048");                      \
    DSR(aR2[2][1], _pa1, "4096"); DSR(aR2[3][1], _pa1, "6144");               \
  } while (0)

#define MFMA_G(AS, qm, qn) do {                                               \
    __builtin_amdgcn_s_setprio(1);                                           \
    _Pragma("unroll")                                                         \
    for (int il = 0; il < 4; ++il)                                            \
      _Pragma("unroll")                                                       \
      for (int jj = 0; jj < 2; ++jj) {                                        \
        f32x4& ac = acc[(qm) * 4 + il][(qn) * 2 + jj];                        \
        ac = __builtin_amdgcn_mfma_f32_16x16x32_bf16(                         \
            __builtin_bit_cast(bf16x8, AS[il][0]),                            \
            __builtin_bit_cast(bf16x8, bR[(qn) * 2 + jj][0]), ac, 0, 0, 0);   \
        ac = __builtin_amdgcn_mfma_f32_16x16x32_bf16(                         \
            __builtin_bit_cast(bf16x8, AS[il][1]),                            \
            __builtin_bit_cast(bf16x8, bR[(qn) * 2 + jj][1]), ac, 0, 0, 0);   \
      }                                                                       \
    __builtin_amdgcn_s_setprio(0);                                           \
  } while (0)

#define WAITL(n) do { asm volatile("s_waitcnt lgkmcnt(" #n ")");              \
                      __builtin_amdgcn_sched_barrier(0); } while (0)
#define WAITV0   do { asm volatile("s_waitcnt vmcnt(0)");                     \
                      __builtin_amdgcn_sched_barrier(0); } while (0)
#define BAR __builtin_amdgcn_s_barrier()

  // prologue
  STAGE(0, 0);
  WAITV0;                 // cold: tile0 staged
  BAR;
  ISSUE_A0(0);
  ISSUE_REST(0);
  STAGE(1, 1);

  for (int t = 0; t < NT; ++t) {
    const int cur = t & 1, nxt = cur ^ 1;
    // G1: needs Aqm0(t)+B01(t) = oldest 12 ds ops
    WAITL(12);
    MFMA_G(aR, 0, 0);
    // G2: needs + B23(t) (next 4 in order)
    WAITL(8);
    MFMA_G(aR, 0, 1);
    if (t < NT - 1) {
      WAITV0;             // stage(t+1) done (issued a tile ago)
      BAR;                // all waves' staging of buf nxt visible
      ISSUE_A0(nxt);      // Aqm0(t+1): drains under G3/G4 MFMAs
      // G3: needs Aqm1(t); in-order DS retirement -> count==8 means the
      // only outstanding ops are the 8 new Aqm0 reads.
      WAITL(8);
      MFMA_G(aR2, 1, 0);  // uses bR[0..1] (old, intact)
      MFMA_G(aR2, 1, 1);  // uses bR[2..3] (old, intact)
      BAR;                // all waves' tile-t reads retired
      ISSUE_REST(nxt);    // B01/B23/Aqm1(t+1): overwrites bR/aR2 (consumed)
      if (t < NT - 2) STAGE(t + 2, cur);
    } else {
      WAITL(0);
      MFMA_G(aR2, 1, 0);
      MFMA_G(aR2, 1, 1);
    }
  }

#undef STG
#undef STAGE
#undef DSR0
#undef DSR
#undef ISSUE_A0
#undef ISSUE_REST
#undef MFMA_G
#undef WAITL
#undef WAITV0
#undef BAR

  // ---- epilogue: scatter to q/k/v planes (C/D layout col=lane&15,
  //      row=(lane>>4)*4+r); wave owns rows [m0+wm,+128), cols = one 64-d head.
  const int cr = (lane >> 4) * 4;
  const int cc = lane & 15;
  const int ncol  = n0 + wn;             // multiple of 64 -> single (plane,head)
  const int which = ncol >> 10;
  const int hh    = (ncol >> 6) & 15;
  const int rowb  = m0 + wm;
  const int bb_   = rowb >> 12;
  const int tb    = rowb & 4095;
  bf16* Cp = qkvOut + (size_t)which * QKVSZ + (size_t)(bb_ * NH + hh) * SEQ * DH;
#pragma unroll
  for (int i = 0; i < 8; ++i)
#pragma unroll
    for (int j = 0; j < 4; ++j)
#pragma unroll
      for (int r = 0; r < 4; ++r)
        Cp[(size_t)(tb + i * 16 + cr + r) * DH + j * 16 + cc] = (bf16)acc[i][j][r];

  // fused agent pooling (q plane only): all 128 rows lie in one 512-t bucket.
  if (which == 0) {
    const int pp = tb >> 9;
    float* ag = agentSum + ((size_t)(bb_ * NH + hh) * POOL + pp) * DH;
#pragma unroll
    for (int j = 0; j < 4; ++j) {
      float s = 0.f;
#pragma unroll
      for (int i = 0; i < 8; ++i)
        s += acc[i][j][0] + acc[i][j][1] + acc[i][j][2] + acc[i][j][3];
      s += __shfl_xor(s, 16);
      s += __shfl_xor(s, 32);
      if (lane < 16) atomicAdd(&ag[j * 16 + lane], s);
    }
  }
}

// ---------------- MFMA GEMM (legacy 128^2 structure), MODE 2 only ----------
// MODE 2: fp32 out row-major + fp32 bias, B batched per 4096 rows of A.
template <int MODE>
__global__ __launch_bounds__(256)
void gemm_bt(const bf16* __restrict__ A, const bf16* __restrict__ B,
             void* __restrict__ Cv, const float* __restrict__ bias,
             float* __restrict__ agentSum, int M, int N, int K) {
  __shared__ bf16 As[128 * 32];
  __shared__ bf16 Bs[128 * 32];
  const int tid  = threadIdx.x;
  const int w    = tid >> 6;
  const int lane = tid & 63;
  const int m0 = blockIdx.y * 128, n0 = blockIdx.x * 128;
  const int wm = (w & 1) * 64, wn = (w >> 1) * 64;

  const bf16* Bb = (MODE == 2) ? (B + (size_t)(m0 >> 12) * N * K) : B;

  f32x4 acc[4][4] = {};

  const int g0  = w * 2;
  const int rig = lane >> 2;
  const int kcs = (lane & 3) ^ ((rig >> 1) & 3);
  const bf16* Ap0 = A + (size_t)(m0 + g0 * 16 + rig) * K + kcs * 8;
  const bf16* Ap1 = Ap0 + (size_t)16 * K;
  const bf16* Bp0 = Bb + (size_t)(n0 + g0 * 16 + rig) * K + kcs * 8;
  const bf16* Bp1 = Bp0 + (size_t)16 * K;
  bf16* AsW0 = As + g0 * 512;
  bf16* AsW1 = As + (g0 + 1) * 512;
  bf16* BsW0 = Bs + g0 * 512;
  bf16* BsW1 = Bs + (g0 + 1) * 512;

  for (int k0 = 0; k0 < K; k0 += 32) {
    __syncthreads();
    __builtin_amdgcn_global_load_lds(AS1(Ap0 + k0), AS3(AsW0), 16, 0, 0);
    __builtin_amdgcn_global_load_lds(AS1(Ap1 + k0), AS3(AsW1), 16, 0, 0);
    __builtin_amdgcn_global_load_lds(AS1(Bp0 + k0), AS3(BsW0), 16, 0, 0);
    __builtin_amdgcn_global_load_lds(AS1(Bp1 + k0), AS3(BsW1), 16, 0, 0);
    __syncthreads();

    bf16x8 a[4], b[4];
    const int C = lane >> 4;
#pragma unroll
    for (int i = 0; i < 4; ++i) {
      int ar = wm + i * 16 + (lane & 15);
      int sw = C ^ ((ar >> 1) & 3);
      a[i] = *(const bf16x8*)&As[ar * 32 + sw * 8];
    }
#pragma unroll
    for (int j = 0; j < 4; ++j) {
      int br = wn + j * 16 + (lane & 15);
      int sw = C ^ ((br >> 1) & 3);
      b[j] = *(const bf16x8*)&Bs[br * 32 + sw * 8];
    }
#pragma unroll
    for (int i = 0; i < 4; ++i)
#pragma unroll
      for (int j = 0; j < 4; ++j)
        acc[i][j] = __builtin_amdgcn_mfma_f32_16x16x32_bf16(a[i], b[j], acc[i][j], 0, 0, 0);
  }

  const int cr = (lane >> 4) * 4;
  const int cc = lane & 15;
#pragma unroll
  for (int i = 0; i < 4; ++i) {
#pragma unroll
    for (int j = 0; j < 4; ++j) {
      int rowb = m0 + wm + i * 16 + cr;
      if (MODE == 2) {
        float* Cp = (float*)Cv;
        int col = n0 + wn + j * 16 + cc;
        float bb = bias[col];
#pragma unroll
        for (int r = 0; r < 4; ++r)
          Cp[(size_t)(rowb + r) * N + col] = acc[i][j][r] + bb;
      } else {
        bf16* Cp = (bf16*)Cv;
        int nbase = n0 + wn + j * 16;
        int which = nbase >> 10;
        int hh    = (nbase >> 6) & 15;
        int dd    = (nbase & 63) + cc;
        int bb_   = rowb >> 12;
#pragma unroll
        for (int r = 0; r < 4; ++r) {
          int t = (rowb + r) & 4095;
          size_t addr = (size_t)which * QKVSZ +
                        ((size_t)(bb_ * NH + hh) * SEQ + t) * DH + dd;
          Cp[addr] = (bf16)acc[i][j][r];
        }
      }
    }
  }
}

// ---- stage 1 fused: scores + chunk softmax + P@V partial, per (bh, t-chunk) ----
__global__ __launch_bounds__(256)
void stage1_fused(const bf16* __restrict__ k, const bf16* __restrict__ v,
                  const float* __restrict__ agentSum,
                  float* __restrict__ pm, float* __restrict__ pl,
                  float* __restrict__ pva) {
  const int tc = blockIdx.x, bh = blockIdx.y;
  const int tid = threadIdx.x;
  const int t0 = tc * TCL;

  __shared__ float agT[64][8];           // [d][p], scaled by SCALE/512
  __shared__ float se[TCL][9];           // exp(sc-m), pad to 9
  __shared__ float rm[4][8], rl[4][8];
  __shared__ float pr[4][8][64];         // [to][p][d] partial PV

  for (int i = tid; i < 512; i += 256) {
    int p = i >> 6, d = i & 63;
    agT[d][p] = agentSum[(size_t)bh * 512 + i] * AGS_F;
  }
  __syncthreads();

  const bf16* krow = k + ((size_t)bh * SEQ + t0 + tid) * DH;
  float sc[8] = {};
#pragma unroll
  for (int dc = 0; dc < 8; ++dc) {
    bf16x8 k8 = *(const bf16x8*)(krow + dc * 8);
#pragma unroll
    for (int e = 0; e < 8; ++e) {
      float kv = (float)k8[e];
      int d = dc * 8 + e;
      float4 a0 = *(const float4*)&agT[d][0];
      float4 a1 = *(const float4*)&agT[d][4];
      sc[0] += a0.x * kv; sc[1] += a0.y * kv; sc[2] += a0.z * kv; sc[3] += a0.w * kv;
      sc[4] += a1.x * kv; sc[5] += a1.y * kv; sc[6] += a1.z * kv; sc[7] += a1.w * kv;
    }
  }

  float mx[8];
#pragma unroll
  for (int p = 0; p < 8; ++p) mx[p] = sc[p];
#pragma unroll
  for (int o = 32; o; o >>= 1)
#pragma unroll
    for (int p = 0; p < 8; ++p) mx[p] = fmaxf(mx[p], __shfl_xor(mx[p], o));
  if ((tid & 63) == 0)
#pragma unroll
    for (int p = 0; p < 8; ++p) rm[tid >> 6][p] = mx[p];
  __syncthreads();
  float m[8];
#pragma unroll
  for (int p = 0; p < 8; ++p)
    m[p] = fmaxf(fmaxf(rm[0][p], rm[1][p]), fmaxf(rm[2][p], rm[3][p]));

  float sl[8];
#pragma unroll
  for (int p = 0; p < 8; ++p) {
    float e = __expf(sc[p] - m[p]);
    se[tid][p] = e;
    sl[p] = e;
  }
#pragma unroll
  for (int o = 32; o; o >>= 1)
#pragma unroll
    for (int p = 0; p < 8; ++p) sl[p] += __shfl_xor(sl[p], o);
  if ((tid & 63) == 0)
#pragma unroll
    for (int p = 0; p < 8; ++p) rl[tid >> 6][p] = sl[p];
  __syncthreads();
  if (tid < 8) {
    float l = rl[0][tid] + rl[1][tid] + rl[2][tid] + rl[3][tid];
    pm[(size_t)(bh * TCH + tc) * 8 + tid] = m[tid];
    pl[(size_t)(bh * TCH + tc) * 8 + tid] = l;
  }

  const int p  = tid >> 5;
  const int dg = tid & 7;
  const int to = (tid >> 3) & 3;
  const bf16* vb = v + ((size_t)bh * SEQ + t0 + to) * DH + dg * 8;
  float a8[8] = {};
  for (int tl = to; tl < TCL; tl += 4) {
    float wgt = se[tl][p];
    bf16x8 v8 = *(const bf16x8*)(vb + (size_t)(tl - to) * DH);
#pragma unroll
    for (int e = 0; e < 8; ++e) a8[e] += wgt * (float)v8[e];
  }
#pragma unroll
  for (int e = 0; e < 8; ++e) pr[to][p][dg * 8 + e] = a8[e];
  __syncthreads();
  if (to == 0) {
    float* o = pva + ((size_t)(bh * TCH + tc) * 8 + p) * DH + dg * 8;
#pragma unroll
    for (int e = 0; e < 8; ++e)
      o[e] = pr[0][p][dg * 8 + e] + pr[1][p][dg * 8 + e] +
             pr[2][p][dg * 8 + e] + pr[3][p][dg * 8 + e];
  }
}

// ---------------- combine chunk partials -> v_agent[bh][p][d] ----------------
__global__ void combine_vag(const float* __restrict__ pm, const float* __restrict__ pl,
                            const float* __restrict__ pva, float* __restrict__ vag) {
  int bh = blockIdx.x;
#pragma unroll
  for (int e = threadIdx.x; e < 512; e += 256) {
    int p = e >> 6, d = e & 63;
    float M = -1e30f;
#pragma unroll
    for (int tc = 0; tc < TCH; ++tc)
      M = fmaxf(M, pm[(size_t)(bh * TCH + tc) * 8 + p]);
    float L = 0.f, acc = 0.f;
#pragma unroll
    for (int tc = 0; tc < TCH; ++tc) {
      float w = __expf(pm[(size_t)(bh * TCH + tc) * 8 + p] - M);
      L   += w * pl[(size_t)(bh * TCH + tc) * 8 + p];
      acc += w * pva[((size_t)(bh * TCH + tc) * 8 + p) * DH + d];
    }
    vag[(size_t)bh * 512 + e] = acc / L;
  }
}

// ---- W2T[b][n][hp] = sum_d vag[b][hp][d] * WoT[n][h*64+d]  (bf16 out) ----
__global__ void w2_build(const float* __restrict__ vag, const bf16* __restrict__ WoT,
                         bf16* __restrict__ W2T) {
  int b = blockIdx.y;
  int n = blockIdx.x * 16 + (threadIdx.x & 15);
  int h = threadIdx.x >> 4;
  __shared__ float vg[128][65];
  for (int i = threadIdx.x; i < 128 * 64; i += 256)
    vg[i >> 6][i & 63] = vag[(size_t)b * 128 * 64 + i];
  __syncthreads();
  float acc[8] = {};
  const bf16* wrow = WoT + (size_t)n * DIMV + h * 64;
#pragma unroll
  for (int dv = 0; dv < 8; ++dv) {
    bf16x8 wv = *(const bf16x8*)(wrow + dv * 8);
#pragma unroll
    for (int e = 0; e < 8; ++e) {
      float wf = (float)wv[e];
      int d = dv * 8 + e;
#pragma unroll
      for (int p = 0; p < 8; ++p) acc[p] += vg[h * 8 + p][d] * wf;
    }
  }
  bf16x8 o;
#pragma unroll
  for (int p = 0; p < 8; ++p) o[p] = (bf16)acc[p];
  *(bf16x8*)&W2T[((size_t)b * DIMV + n) * HP + h * 8] = o;
}

// ---- P2[b*4096+t][h*8+p] = softmax_p(q . agent * SCALE)  (bf16) ----
__global__ __launch_bounds__(256)
void p2_build(const bf16* __restrict__ q, const float* __restrict__ agentSum,
              bf16* __restrict__ P2) {
  const int bh = blockIdx.y;
  const int t  = blockIdx.x * 256 + threadIdx.x;
  const int tid = threadIdx.x;

  __shared__ float agT[64][8];
  for (int i = tid; i < 512; i += 256) {
    int p = i >> 6, d = i & 63;
    agT[d][p] = agentSum[(size_t)bh * 512 + i] * AGS_F;
  }
  __syncthreads();

  const bf16* qrow = q + ((size_t)bh * SEQ + t) * DH;
  float sc[8] = {};
#pragma unroll
  for (int dc = 0; dc < 8; ++dc) {
    bf16x8 q8 = *(const bf16x8*)(qrow + dc * 8);
#pragma unroll
    for (int e = 0; e < 8; ++e) {
      float qv = (float)q8[e];
      int d = dc * 8 + e;
      float4 a0 = *(const float4*)&agT[d][0];
      float4 a1 = *(const float4*)&agT[d][4];
      sc[0] += a0.x * qv; sc[1] += a0.y * qv; sc[2] += a0.z * qv; sc[3] += a0.w * qv;
      sc[4] += a1.x * qv; sc[5] += a1.y * qv; sc[6] += a1.z * qv; sc[7] += a1.w * qv;
    }
  }
  float m = sc[0];
#pragma unroll
  for (int p = 1; p < 8; ++p) m = fmaxf(m, sc[p]);
  float wsum = 0.f, wgt[8];
#pragma unroll
  for (int p = 0; p < 8; ++p) { wgt[p] = __expf(sc[p] - m); wsum += wgt[p]; }
  float inv = 1.0f / wsum;
  int b = bh >> 4, h = bh & 15;
  bf16x8 o8;
#pragma unroll
  for (int p = 0; p < 8; ++p) o8[p] = (bf16)(wgt[p] * inv);
  *(bf16x8*)&P2[((size_t)(b * SEQ + t)) * HP + h * 8] = o8;
}

extern "C" void kernel_launch(void* const* d_in, const int* in_sizes, int n_in,
                              void* d_out, int out_size, void* d_ws, size_t ws_size,
                              hipStream_t stream) {
  const float* x    = (const float*)d_in[0];   // [4,4096,1024] fp32
  const float* Wqkv = (const float*)d_in[1];   // [1024,3072]   fp32
  const float* Wo   = (const float*)d_in[2];   // [1024,1024]   fp32
  const float* bo   = (const float*)d_in[3];   // [1024]        fp32
  float* out = (float*)d_out;                  // [4,4096,1024] fp32

  char* ws = (char*)d_ws;
  bf16* WqkvT = (bf16*)ws;                                   ws += (size_t)QKV_N * DIMV * 2;
  bf16* WoT   = (bf16*)ws;                                   ws += (size_t)DIMV * DIMV * 2;
  bf16* qkv   = (bf16*)ws;                                   ws += 3 * QKVSZ * 2;
  char* wsu   = ws;                                          ws += (size_t)M_TOTAL * DIMV * 2;
  bf16*  xb    = (bf16*)wsu;
  bf16*  P2    = (bf16*)wsu;                                  // 4 MB (after xb dead)
  bf16*  W2T   = (bf16*)(wsu + (size_t)M_TOTAL * HP * 2);     // 1 MB
  float* agent = (float*)ws;                                 ws += 512 * 64 * 4;
  float* pm    = (float*)ws;                                 ws += BH * TCH * 8 * 4;
  float* pl    = (float*)ws;                                 ws += BH * TCH * 8 * 4;
  float* pva   = (float*)ws;                                 ws += (size_t)BH * TCH * 8 * DH * 4;
  float* vag   = (float*)ws;                                 ws += 512 * 64 * 4;

  const bf16* qp = qkv;
  const bf16* kp = qkv + QKVSZ;
  const bf16* vp = qkv + 2 * QKVSZ;

  // agent accumulated by GEMM1-epilogue atomics -> zero it first
  hipMemsetAsync(agent, 0, 512 * 64 * 4, stream);

  convert_x<<<(size_t)M_TOTAL * DIMV / (256 * 8), 256, 0, stream>>>(x, xb);
  transpose_f32_bf16<<<dim3(QKV_N / 32, DIMV / 32), 256, 0, stream>>>(Wqkv, WqkvT, DIMV, QKV_N);
  transpose_f32_bf16<<<dim3(DIMV / 32, DIMV / 32), 256, 0, stream>>>(Wo, WoT, DIMV, DIMV);

  // GEMM1: qkv = x @ Wqkv (split planes) + fused q pooling sums
  // 256^2 tile, counted-lgkm pipelined schedule: grid 768 = (3072/256)*(16384/256)
  gemm1_qkv<<<768, 512, 0, stream>>>(xb, WqkvT, qkv, agent);

  p2_build<<<dim3(SEQ / 256, BH), 256, 0, stream>>>(qp, agent, P2);
  stage1_fused<<<dim3(TCH, BH), 256, 0, stream>>>(kp, vp, agent, pm, pl, pva);
  combine_vag<<<BH, 256, 0, stream>>>(pm, pl, pva, vag);
  w2_build<<<dim3(DIMV / 16, BATCH), 256, 0, stream>>>(vag, WoT, W2T);

  // out = P2 @ W2T(batched) + bo   (fp32 out, K=128)
  gemm_bt<2><<<dim3(DIMV / 128, M_TOTAL / 128), 256, 0, stream>>>(
      P2, W2T, (void*)out, bo, nullptr, M_TOTAL, DIMV, HP);
}

// Round 5
// 317.708 us; speedup vs baseline: 1.0302x; 1.0302x over previous
//
#include <hip/hip_runtime.h>
#include <hip/hip_bf16.h>
#include <stdint.h>

typedef __bf16 bf16;
typedef __attribute__((ext_vector_type(8))) __bf16 bf16x8;
typedef __attribute__((ext_vector_type(4))) float f32x4;
typedef __attribute__((ext_vector_type(4))) unsigned int u32x4;

#define NH 16
#define DH 64
#define POOL 8
#define BATCH 4
#define SEQ 4096
#define DIMV 1024
#define QKV_N (3*DIMV)
#define M_TOTAL (BATCH*SEQ)
#define SCALE_F 0.125f
// agent buffer holds SUMS over 512 t (from GEMM1-epilogue atomics);
// consumers fold mean (1/512) into the pre-softmax dot: exact.
#define AGS_F (SCALE_F / 512.0f)
#define BH (BATCH*NH)              // 64
#define QKVSZ ((size_t)BH*SEQ*DH)  // elems per q/k/v plane
#define TCH 16                     // t-split chunks for stage1
#define TCL (SEQ/TCH)              // 256 t per chunk
#define HP 128                     // h*p combined dim for P2/W2

#define AS1(p) ((const __attribute__((address_space(1))) void*)(p))
#define AS3(p) ((__attribute__((address_space(3))) void*)(p))
typedef const __attribute__((address_space(3))) char* lds_cp;

// ---------------- fused prep: x->bf16 convert + both weight transposes ------
// block ranges: [0,8192) convert_x; [8192,11264) Wqkv transpose; rest Wo.
__global__ void prep(const float* __restrict__ x, bf16* __restrict__ xb,
                     const float* __restrict__ Wqkv, bf16* __restrict__ WqkvT,
                     const float* __restrict__ Wo, bf16* __restrict__ WoT) {
  __shared__ float tile[32][33];
  const int b = blockIdx.x;
  if (b < 8192) {
    size_t i = ((size_t)b * 256 + threadIdx.x) * 8;
    float4 f0 = *(const float4*)(x + i);
    float4 f1 = *(const float4*)(x + i + 4);
    bf16x8 o;
    o[0] = (bf16)f0.x; o[1] = (bf16)f0.y; o[2] = (bf16)f0.z; o[3] = (bf16)f0.w;
    o[4] = (bf16)f1.x; o[5] = (bf16)f1.y; o[6] = (bf16)f1.z; o[7] = (bf16)f1.w;
    *(bf16x8*)(xb + i) = o;
    return;
  }
  const float* in; bf16* out; int C, bx, by;
  if (b < 8192 + 3072) { int bb = b - 8192;  in = Wqkv; out = WqkvT; C = QKV_N; bx = bb % 96; by = bb / 96; }
  else                 { int bb = b - 11264; in = Wo;   out = WoT;   C = DIMV;  bx = bb % 32; by = bb / 32; }
  const int R = DIMV;
  int c0 = bx * 32, r0 = by * 32;
  int tx = threadIdx.x & 31, ty = threadIdx.x >> 5;
  for (int i = ty; i < 32; i += 8)
    tile[i][tx] = in[(size_t)(r0 + i) * C + c0 + tx];
  __syncthreads();
  for (int i = ty; i < 32; i += 8)
    out[(size_t)(c0 + i) * R + r0 + tx] = (bf16)tile[tx][i];
}

// ============================================================================
// GEMM1: 256x256 tile, BK=64, 8 waves, 8-phase schedule.  BYTE-IDENTICAL to
// the R1 kernel (verified: 106.5us, MfmaUtil 41%, bank conflicts 0, passed).
// R2/R3 counted-lgkm restructures both lost to this (race / -10% regression):
// the fine-grained phase interleave distributes ds_read issue between MFMA
// quadrants; coarse read-clumping stalls all 8 lockstep waves together.
// ============================================================================
__global__ __launch_bounds__(512, 2)
void gemm1_qkv(const bf16* __restrict__ A, const bf16* __restrict__ B,
               bf16* __restrict__ qkvOut, float* __restrict__ agentSum) {
  constexpr int K1 = DIMV;       // 1024
  constexpr int NI = K1 / 128;   // 8 pipeline iterations (2 K-tiles each)

  __shared__ __align__(16) bf16 LA[2][2][8192];   // [buf][half][128*64]
  __shared__ __align__(16) bf16 LB[2][2][8192];

  const int tid  = threadIdx.x;
  const int w    = tid >> 6;
  const int lane = tid & 63;
  const int wm = (w >> 2) * 128;         // 2 M-waves x 4 N-waves
  const int wn = (w & 3) * 64;

  // bijective XCD swizzle (768 % 8 == 0)
  const int bid = blockIdx.x;
  const int swz = (bid & 7) * 96 + (bid >> 3);
  const int m0 = (swz / 12) * 256;
  const int n0 = (swz % 12) * 256;

  // staging: thread t covers (row rT + 64*e + 128*half, 16B slot t&7);
  // source column pre-swizzled so linear LDS dest realizes slot^(row&7).
  const int rT  = tid >> 3;
  const int csT = (((tid & 7) ^ (rT & 7)) << 3);
  const bf16* Ag = A + (size_t)(m0 + rT) * K1 + csT;
  const bf16* Bg = B + (size_t)(n0 + rT) * K1 + csT;

  // ds_read lane constants: row rA within 16-row frag, k-group C, xor rA&7
  const int rA = lane & 15, C = lane >> 4, xr = rA & 7;
  const unsigned s0 = (unsigned)(((0 * 4 + C) ^ xr) << 4);   // ks=0 slot byte
  const unsigned s1 = (unsigned)(((1 * 4 + C) ^ xr) << 4);   // ks=1 slot byte
  const unsigned aoff = (unsigned)((wm + rA) << 7);          // folds half+row
  const unsigned boff = (unsigned)((wn + rA) << 7);

  f32x4 acc[8][4] = {};
  u32x4 aR[4][2], bR[4][2];

#define STG(arr, Gp, half, kofs) do {                                         \
    const bf16* _s = (Gp) + (size_t)((half) * 128) * K1 + (kofs);             \
    char* _d = (char*)&arr[half][0] + (w << 10);                              \
    __builtin_amdgcn_global_load_lds(AS1(_s), AS3(_d), 16, 0, 0);             \
    __builtin_amdgcn_global_load_lds(AS1(_s + 64 * K1), AS3(_d + 8192), 16, 0, 0); \
  } while (0)

#define DSR0(d, p)    asm volatile("ds_read_b128 %0, %1" : "=v"(d) : "v"(p))
#define DSR(d, p, o)  asm volatile("ds_read_b128 %0, %1 offset:" o : "=v"(d) : "v"(p))

#define READS_A(LAb, qm) do {                                                 \
    lds_cp _p0 = (lds_cp)(const char*)&LAb[0][0] + aoff + s0 + (qm) * 8192;   \
    lds_cp _p1 = (lds_cp)(const char*)&LAb[0][0] + aoff + s1 + (qm) * 8192;   \
    DSR0(aR[0][0], _p0); DSR(aR[1][0], _p0, "2048");                          \
    DSR(aR[2][0], _p0, "4096"); DSR(aR[3][0], _p0, "6144");                   \
    DSR0(aR[0][1], _p1); DSR(aR[1][1], _p1, "2048");                          \
    DSR(aR[2][1], _p1, "4096"); DSR(aR[3][1], _p1, "6144");                   \
  } while (0)

#define READS_B01(LBb) do {                                                   \
    lds_cp _p0 = (lds_cp)(const char*)&LBb[0][0] + boff + s0;                 \
    lds_cp _p1 = (lds_cp)(const char*)&LBb[0][0] + boff + s1;                 \
    DSR0(bR[0][0], _p0); DSR(bR[1][0], _p0, "2048");                          \
    DSR0(bR[0][1], _p1); DSR(bR[1][1], _p1, "2048");                          \
  } while (0)

#define READS_B23(LBb) do {                                                   \
    lds_cp _p0 = (lds_cp)(const char*)&LBb[0][0] + boff + s0;                 \
    lds_cp _p1 = (lds_cp)(const char*)&LBb[0][0] + boff + s1;                 \
    DSR(bR[2][0], _p0, "4096"); DSR(bR[3][0], _p0, "6144");                   \
    DSR(bR[2][1], _p1, "4096"); DSR(bR[3][1], _p1, "6144");                   \
  } while (0)

#define MFMA_Q(qm, qn) do {                                                   \
    asm volatile("s_waitcnt lgkmcnt(0)");                                     \
    __builtin_amdgcn_sched_barrier(0);                                        \
    __builtin_amdgcn_s_setprio(1);                                            \
    _Pragma("unroll")                                                         \
    for (int il = 0; il < 4; ++il)                                            \
      _Pragma("unroll")                                                       \
      for (int jj = 0; jj < 2; ++jj) {                                        \
        f32x4& ac = acc[(qm) * 4 + il][(qn) * 2 + jj];                        \
        ac = __builtin_amdgcn_mfma_f32_16x16x32_bf16(                         \
            __builtin_bit_cast(bf16x8, aR[il][0]),                            \
            __builtin_bit_cast(bf16x8, bR[(qn) * 2 + jj][0]), ac, 0, 0, 0);   \
        ac = __builtin_amdgcn_mfma_f32_16x16x32_bf16(                         \
            __builtin_bit_cast(bf16x8, aR[il][1]),                            \
            __builtin_bit_cast(bf16x8, bR[(qn) * 2 + jj][1]), ac, 0, 0, 0);   \
      }                                                                       \
    __builtin_amdgcn_s_setprio(0);                                            \
    __builtin_amdgcn_sched_barrier(0);                                        \
  } while (0)

#define BAR __builtin_amdgcn_s_barrier()

  // prologue: tile0 (A+B) -> buf0; tile1 B -> buf1   (12 issues)
  STG(LA[0], Ag, 0, 0); STG(LA[0], Ag, 1, 0);
  STG(LB[0], Bg, 0, 0); STG(LB[0], Bg, 1, 0);
  STG(LB[1], Bg, 0, 64); STG(LB[1], Bg, 1, 64);
  asm volatile("s_waitcnt vmcnt(4)");    // buf0 tile landed; buf1 B in flight
  __builtin_amdgcn_sched_barrier(0);
  BAR;

  int kk = 0;
  for (int i = 0; i < NI - 1; ++i, kk += 128) {
    // ---- phases 1-4: consume buf0 (tile 2i) ----
    READS_A(LA[0], 0); READS_B01(LB[0]);
    STG(LA[1], Ag, 0, kk + 64);          // ph1: buf1.A0 <- tile 2i+1
    BAR; MFMA_Q(0, 0); BAR;
    READS_B23(LB[0]);
    STG(LA[1], Ag, 1, kk + 64);          // ph2: buf1.A1 <- tile 2i+1
    BAR; MFMA_Q(0, 1); BAR;
    READS_A(LA[0], 1);
    STG(LB[0], Bg, 0, kk + 128);         // ph3: buf0.B0 <- tile 2i+2
    BAR; MFMA_Q(1, 0); BAR;
    STG(LB[0], Bg, 1, kk + 128);         // ph4: buf0.B1 <- tile 2i+2
    BAR; MFMA_Q(1, 1);
    asm volatile("s_waitcnt vmcnt(4)");  // buf1 tile 2i+1 landed
    __builtin_amdgcn_sched_barrier(0);
    BAR;
    // ---- phases 5-8: consume buf1 (tile 2i+1) ----
    READS_A(LA[1], 0); READS_B01(LB[1]);
    STG(LA[0], Ag, 0, kk + 128);         // ph5: buf0.A0 <- tile 2i+2
    BAR; MFMA_Q(0, 0); BAR;
    READS_B23(LB[1]);
    STG(LA[0], Ag, 1, kk + 128);         // ph6: buf0.A1 <- tile 2i+2
    BAR; MFMA_Q(0, 1); BAR;
    READS_A(LA[1], 1);
    STG(LB[1], Bg, 0, kk + 192);         // ph7: buf1.B0 <- tile 2i+3
    BAR; MFMA_Q(1, 0); BAR;
    STG(LB[1], Bg, 1, kk + 192);         // ph8: buf1.B1 <- tile 2i+3
    BAR; MFMA_Q(1, 1);
    asm volatile("s_waitcnt vmcnt(4)");  // buf0 tile 2i+2 landed
    __builtin_amdgcn_sched_barrier(0);
    BAR;
  }
  // ---- tail iteration: buf0 = tile NT-2, buf1 = tile NT-1 ----
  READS_A(LA[0], 0); READS_B01(LB[0]);
  STG(LA[1], Ag, 0, kk + 64);            // last A halves of tile NT-1
  BAR; MFMA_Q(0, 0); BAR;
  READS_B23(LB[0]);
  STG(LA[1], Ag, 1, kk + 64);
  BAR; MFMA_Q(0, 1); BAR;
  READS_A(LA[0], 1);
  BAR; MFMA_Q(1, 0); BAR;
  MFMA_Q(1, 1);
  asm volatile("s_waitcnt vmcnt(0)");    // drain: buf1 tile NT-1 landed
  __builtin_amdgcn_sched_barrier(0);
  BAR;
  READS_A(LA[1], 0); READS_B01(LB[1]);
  BAR; MFMA_Q(0, 0); BAR;
  READS_B23(LB[1]);
  BAR; MFMA_Q(0, 1); BAR;
  READS_A(LA[1], 1);
  BAR; MFMA_Q(1, 0); BAR;
  MFMA_Q(1, 1);

#undef STG
#undef DSR0
#undef DSR
#undef READS_A
#undef READS_B01
#undef READS_B23
#undef MFMA_Q
#undef BAR

  // ---- epilogue: scatter to q/k/v planes (C/D layout col=lane&15,
  //      row=(lane>>4)*4+r); wave owns rows [m0+wm,+128), cols = one 64-d head.
  const int cr = (lane >> 4) * 4;
  const int cc = lane & 15;
  const int ncol  = n0 + wn;             // multiple of 64 -> single (plane,head)
  const int which = ncol >> 10;
  const int hh    = (ncol >> 6) & 15;
  const int rowb  = m0 + wm;
  const int bb_   = rowb >> 12;
  const int tb    = rowb & 4095;
  bf16* Cp = qkvOut + (size_t)which * QKVSZ + (size_t)(bb_ * NH + hh) * SEQ * DH;
#pragma unroll
  for (int i = 0; i < 8; ++i)
#pragma unroll
    for (int j = 0; j < 4; ++j)
#pragma unroll
      for (int r = 0; r < 4; ++r)
        Cp[(size_t)(tb + i * 16 + cr + r) * DH + j * 16 + cc] = (bf16)acc[i][j][r];

  // fused agent pooling (q plane only): all 128 rows lie in one 512-t bucket.
  if (which == 0) {
    const int pp = tb >> 9;
    float* ag = agentSum + ((size_t)(bb_ * NH + hh) * POOL + pp) * DH;
#pragma unroll
    for (int j = 0; j < 4; ++j) {
      float s = 0.f;
#pragma unroll
      for (int i = 0; i < 8; ++i)
        s += acc[i][j][0] + acc[i][j][1] + acc[i][j][2] + acc[i][j][3];
      s += __shfl_xor(s, 16);
      s += __shfl_xor(s, 32);
      if (lane < 16) atomicAdd(&ag[j * 16 + lane], s);
    }
  }
}

// ============================================================================
// GEMM2: out = P2 @ W2T(batched)^T + bo.  256x256 tile, K=128 = exactly 2
// K-tiles -> reuses the R1-verified prologue+tail code path (the same
// instruction sequence gemm1's tail executes).  Grid 256 = 1 block/CU,
// single dispatch round (vs legacy 1024 blocks x 4 rounds).  Write-bound:
// 64MB fp32 out.  fp32+bias epilogue.
// ============================================================================
__global__ __launch_bounds__(512, 2)
void gemm2_256(const bf16* __restrict__ A, const bf16* __restrict__ B,
               float* __restrict__ Out, const float* __restrict__ bias) {
  constexpr int K2 = HP;   // 128

  __shared__ __align__(16) bf16 LA[2][2][8192];
  __shared__ __align__(16) bf16 LB[2][2][8192];

  const int tid  = threadIdx.x;
  const int w    = tid >> 6;
  const int lane = tid & 63;
  const int wm = (w >> 2) * 128;
  const int wn = (w & 3) * 64;

  const int bid = blockIdx.x;
  const int swz = (bid & 7) * 32 + (bid >> 3);   // bijective, 256 % 8 == 0
  const int m0 = (swz >> 2) * 256;
  const int n0 = (swz & 3) * 256;

  const int rT  = tid >> 3;
  const int csT = (((tid & 7) ^ (rT & 7)) << 3);
  const bf16* Ag = A + (size_t)(m0 + rT) * K2 + csT;
  // B = W2T [batch][n][hp]; 256 | 4096 -> whole M-tile in one batch
  const bf16* Bg = B + ((size_t)(m0 >> 12) * DIMV + n0 + rT) * K2 + csT;

  const int rA = lane & 15, C = lane >> 4, xr = rA & 7;
  const unsigned s0 = (unsigned)(((0 * 4 + C) ^ xr) << 4);
  const unsigned s1 = (unsigned)(((1 * 4 + C) ^ xr) << 4);
  const unsigned aoff = (unsigned)((wm + rA) << 7);
  const unsigned boff = (unsigned)((wn + rA) << 7);

  f32x4 acc[8][4] = {};
  u32x4 aR[4][2], bR[4][2];

#define STG(arr, Gp, half, kofs) do {                                         \
    const bf16* _s = (Gp) + (size_t)((half) * 128) * K2 + (kofs);             \
    char* _d = (char*)&arr[half][0] + (w << 10);                              \
    __builtin_amdgcn_global_load_lds(AS1(_s), AS3(_d), 16, 0, 0);             \
    __builtin_amdgcn_global_load_lds(AS1(_s + 64 * K2), AS3(_d + 8192), 16, 0, 0); \
  } while (0)

#define DSR0(d, p)    asm volatile("ds_read_b128 %0, %1" : "=v"(d) : "v"(p))
#define DSR(d, p, o)  asm volatile("ds_read_b128 %0, %1 offset:" o : "=v"(d) : "v"(p))

#define READS_A(LAb, qm) do {                                                 \
    lds_cp _p0 = (lds_cp)(const char*)&LAb[0][0] + aoff + s0 + (qm) * 8192;   \
    lds_cp _p1 = (lds_cp)(const char*)&LAb[0][0] + aoff + s1 + (qm) * 8192;   \
    DSR0(aR[0][0], _p0); DSR(aR[1][0], _p0, "2048");                          \
    DSR(aR[2][0], _p0, "4096"); DSR(aR[3][0], _p0, "6144");                   \
    DSR0(aR[0][1], _p1); DSR(aR[1][1], _p1, "2048");                          \
    DSR(aR[2][1], _p1, "4096"); DSR(aR[3][1], _p1, "6144");                   \
  } while (0)

#define READS_B01(LBb) do {                                                   \
    lds_cp _p0 = (lds_cp)(const char*)&LBb[0][0] + boff + s0;                 \
    lds_cp _p1 = (lds_cp)(const char*)&LBb[0][0] + boff + s1;                 \
    DSR0(bR[0][0], _p0); DSR(bR[1][0], _p0, "2048");                          \
    DSR0(bR[0][1], _p1); DSR(bR[1][1], _p1, "2048");                          \
  } while (0)

#define READS_B23(LBb) do {                                                   \
    lds_cp _p0 = (lds_cp)(const char*)&LBb[0][0] + boff + s0;                 \
    lds_cp _p1 = (lds_cp)(const char*)&LBb[0][0] + boff + s1;                 \
    DSR(bR[2][0], _p0, "4096"); DSR(bR[3][0], _p0, "6144");                   \
    DSR(bR[2][1], _p1, "4096"); DSR(bR[3][1], _p1, "6144");                   \
  } while (0)

#define MFMA_Q(qm, qn) do {                                                   \
    asm volatile("s_waitcnt lgkmcnt(0)");                                     \
    __builtin_amdgcn_sched_barrier(0);                                        \
    __builtin_amdgcn_s_setprio(1);                                            \
    _Pragma("unroll")                                                         \
    for (int il = 0; il < 4; ++il)                                            \
      _Pragma("unroll")                                                       \
      for (int jj = 0; jj < 2; ++jj) {                                        \
        f32x4& ac = acc[(qm) * 4 + il][(qn) * 2 + jj];                        \
        ac = __builtin_amdgcn_mfma_f32_16x16x32_bf16(                         \
            __builtin_bit_cast(bf16x8, aR[il][0]),                            \
            __builtin_bit_cast(bf16x8, bR[(qn) * 2 + jj][0]), ac, 0, 0, 0);   \
        ac = __builtin_amdgcn_mfma_f32_16x16x32_bf16(                         \
            __builtin_bit_cast(bf16x8, aR[il][1]),                            \
            __builtin_bit_cast(bf16x8, bR[(qn) * 2 + jj][1]), ac, 0, 0, 0);   \
      }                                                                       \
    __builtin_amdgcn_s_setprio(0);                                            \
    __builtin_amdgcn_sched_barrier(0);                                        \
  } while (0)

#define BAR __builtin_amdgcn_s_barrier()

  // prologue (R1 pattern): tile0 A+B -> buf0; tile1 B -> buf1
  STG(LA[0], Ag, 0, 0); STG(LA[0], Ag, 1, 0);
  STG(LB[0], Bg, 0, 0); STG(LB[0], Bg, 1, 0);
  STG(LB[1], Bg, 0, 64); STG(LB[1], Bg, 1, 64);
  asm volatile("s_waitcnt vmcnt(4)");
  __builtin_amdgcn_sched_barrier(0);
  BAR;

  // tile 0 (R1 tail structure, kk = 0)
  READS_A(LA[0], 0); READS_B01(LB[0]);
  STG(LA[1], Ag, 0, 64);
  BAR; MFMA_Q(0, 0); BAR;
  READS_B23(LB[0]);
  STG(LA[1], Ag, 1, 64);
  BAR; MFMA_Q(0, 1); BAR;
  READS_A(LA[0], 1);
  BAR; MFMA_Q(1, 0); BAR;
  MFMA_Q(1, 1);
  asm volatile("s_waitcnt vmcnt(0)");
  __builtin_amdgcn_sched_barrier(0);
  BAR;
  // tile 1
  READS_A(LA[1], 0); READS_B01(LB[1]);
  BAR; MFMA_Q(0, 0); BAR;
  READS_B23(LB[1]);
  BAR; MFMA_Q(0, 1); BAR;
  READS_A(LA[1], 1);
  BAR; MFMA_Q(1, 0); BAR;
  MFMA_Q(1, 1);

#undef STG
#undef DSR0
#undef DSR
#undef READS_A
#undef READS_B01
#undef READS_B23
#undef MFMA_Q
#undef BAR

  // epilogue: fp32 row-major + bias
  const int cr = (lane >> 4) * 4;
  const int cc = lane & 15;
  const int rowb = m0 + wm;
  float bb4[4];
#pragma unroll
  for (int j = 0; j < 4; ++j) bb4[j] = bias[n0 + wn + j * 16 + cc];
#pragma unroll
  for (int i = 0; i < 8; ++i)
#pragma unroll
    for (int j = 0; j < 4; ++j) {
      const int col = n0 + wn + j * 16 + cc;
#pragma unroll
      for (int r = 0; r < 4; ++r)
        Out[(size_t)(rowb + i * 16 + cr + r) * DIMV + col] = acc[i][j][r] + bb4[j];
    }
}

// ---- stage 1 fused: scores + chunk softmax + P@V partial, per (bh, t-chunk) ----
__global__ __launch_bounds__(256)
void stage1_fused(const bf16* __restrict__ k, const bf16* __restrict__ v,
                  const float* __restrict__ agentSum,
                  float* __restrict__ pm, float* __restrict__ pl,
                  float* __restrict__ pva) {
  const int tc = blockIdx.x, bh = blockIdx.y;
  const int tid = threadIdx.x;
  const int t0 = tc * TCL;

  __shared__ float agT[64][8];           // [d][p], scaled by SCALE/512
  __shared__ float se[TCL][9];           // exp(sc-m), pad to 9
  __shared__ float rm[4][8], rl[4][8];
  __shared__ float pr[4][8][64];         // [to][p][d] partial PV

  for (int i = tid; i < 512; i += 256) {
    int p = i >> 6, d = i & 63;
    agT[d][p] = agentSum[(size_t)bh * 512 + i] * AGS_F;
  }
  __syncthreads();

  const bf16* krow = k + ((size_t)bh * SEQ + t0 + tid) * DH;
  float sc[8] = {};
#pragma unroll
  for (int dc = 0; dc < 8; ++dc) {
    bf16x8 k8 = *(const bf16x8*)(krow + dc * 8);
#pragma unroll
    for (int e = 0; e < 8; ++e) {
      float kv = (float)k8[e];
      int d = dc * 8 + e;
      float4 a0 = *(const float4*)&agT[d][0];
      float4 a1 = *(const float4*)&agT[d][4];
      sc[0] += a0.x * kv; sc[1] += a0.y * kv; sc[2] += a0.z * kv; sc[3] += a0.w * kv;
      sc[4] += a1.x * kv; sc[5] += a1.y * kv; sc[6] += a1.z * kv; sc[7] += a1.w * kv;
    }
  }

  float mx[8];
#pragma unroll
  for (int p = 0; p < 8; ++p) mx[p] = sc[p];
#pragma unroll
  for (int o = 32; o; o >>= 1)
#pragma unroll
    for (int p = 0; p < 8; ++p) mx[p] = fmaxf(mx[p], __shfl_xor(mx[p], o));
  if ((tid & 63) == 0)
#pragma unroll
    for (int p = 0; p < 8; ++p) rm[tid >> 6][p] = mx[p];
  __syncthreads();
  float m[8];
#pragma unroll
  for (int p = 0; p < 8; ++p)
    m[p] = fmaxf(fmaxf(rm[0][p], rm[1][p]), fmaxf(rm[2][p], rm[3][p]));

  float sl[8];
#pragma unroll
  for (int p = 0; p < 8; ++p) {
    float e = __expf(sc[p] - m[p]);
    se[tid][p] = e;
    sl[p] = e;
  }
#pragma unroll
  for (int o = 32; o; o >>= 1)
#pragma unroll
    for (int p = 0; p < 8; ++p) sl[p] += __shfl_xor(sl[p], o);
  if ((tid & 63) == 0)
#pragma unroll
    for (int p = 0; p < 8; ++p) rl[tid >> 6][p] = sl[p];
  __syncthreads();
  if (tid < 8) {
    float l = rl[0][tid] + rl[1][tid] + rl[2][tid] + rl[3][tid];
    pm[(size_t)(bh * TCH + tc) * 8 + tid] = m[tid];
    pl[(size_t)(bh * TCH + tc) * 8 + tid] = l;
  }

  const int p  = tid >> 5;
  const int dg = tid & 7;
  const int to = (tid >> 3) & 3;
  const bf16* vb = v + ((size_t)bh * SEQ + t0 + to) * DH + dg * 8;
  float a8[8] = {};
  for (int tl = to; tl < TCL; tl += 4) {
    float wgt = se[tl][p];
    bf16x8 v8 = *(const bf16x8*)(vb + (size_t)(tl - to) * DH);
#pragma unroll
    for (int e = 0; e < 8; ++e) a8[e] += wgt * (float)v8[e];
  }
#pragma unroll
  for (int e = 0; e < 8; ++e) pr[to][p][dg * 8 + e] = a8[e];
  __syncthreads();
  if (to == 0) {
    float* o = pva + ((size_t)(bh * TCH + tc) * 8 + p) * DH + dg * 8;
#pragma unroll
    for (int e = 0; e < 8; ++e)
      o[e] = pr[0][p][dg * 8 + e] + pr[1][p][dg * 8 + e] +
             pr[2][p][dg * 8 + e] + pr[3][p][dg * 8 + e];
  }
}

// ---------------- combine chunk partials -> v_agent[bh][p][d] ----------------
__global__ void combine_vag(const float* __restrict__ pm, const float* __restrict__ pl,
                            const float* __restrict__ pva, float* __restrict__ vag) {
  int bh = blockIdx.x;
#pragma unroll
  for (int e = threadIdx.x; e < 512; e += 256) {
    int p = e >> 6, d = e & 63;
    float M = -1e30f;
#pragma unroll
    for (int tc = 0; tc < TCH; ++tc)
      M = fmaxf(M, pm[(size_t)(bh * TCH + tc) * 8 + p]);
    float L = 0.f, acc = 0.f;
#pragma unroll
    for (int tc = 0; tc < TCH; ++tc) {
      float w = __expf(pm[(size_t)(bh * TCH + tc) * 8 + p] - M);
      L   += w * pl[(size_t)(bh * TCH + tc) * 8 + p];
      acc += w * pva[((size_t)(bh * TCH + tc) * 8 + p) * DH + d];
    }
    vag[(size_t)bh * 512 + e] = acc / L;
  }
}

// ---- W2T[b][n][hp] = sum_d vag[b][hp][d] * WoT[n][h*64+d]  (bf16 out) ----
__global__ void w2_build(const float* __restrict__ vag, const bf16* __restrict__ WoT,
                         bf16* __restrict__ W2T) {
  int b = blockIdx.y;
  int n = blockIdx.x * 16 + (threadIdx.x & 15);
  int h = threadIdx.x >> 4;
  __shared__ float vg[128][65];
  for (int i = threadIdx.x; i < 128 * 64; i += 256)
    vg[i >> 6][i & 63] = vag[(size_t)b * 128 * 64 + i];
  __syncthreads();
  float acc[8] = {};
  const bf16* wrow = WoT + (size_t)n * DIMV + h * 64;
#pragma unroll
  for (int dv = 0; dv < 8; ++dv) {
    bf16x8 wv = *(const bf16x8*)(wrow + dv * 8);
#pragma unroll
    for (int e = 0; e < 8; ++e) {
      float wf = (float)wv[e];
      int d = dv * 8 + e;
#pragma unroll
      for (int p = 0; p < 8; ++p) acc[p] += vg[h * 8 + p][d] * wf;
    }
  }
  bf16x8 o;
#pragma unroll
  for (int p = 0; p < 8; ++p) o[p] = (bf16)acc[p];
  *(bf16x8*)&W2T[((size_t)b * DIMV + n) * HP + h * 8] = o;
}

// ---- P2[b*4096+t][h*8+p] = softmax_p(q . agent * SCALE)  (bf16) ----
__global__ __launch_bounds__(256)
void p2_build(const bf16* __restrict__ q, const float* __restrict__ agentSum,
              bf16* __restrict__ P2) {
  const int bh = blockIdx.y;
  const int t  = blockIdx.x * 256 + threadIdx.x;
  const int tid = threadIdx.x;

  __shared__ float agT[64][8];
  for (int i = tid; i < 512; i += 256) {
    int p = i >> 6, d = i & 63;
    agT[d][p] = agentSum[(size_t)bh * 512 + i] * AGS_F;
  }
  __syncthreads();

  const bf16* qrow = q + ((size_t)bh * SEQ + t) * DH;
  float sc[8] = {};
#pragma unroll
  for (int dc = 0; dc < 8; ++dc) {
    bf16x8 q8 = *(const bf16x8*)(qrow + dc * 8);
#pragma unroll
    for (int e = 0; e < 8; ++e) {
      float qv = (float)q8[e];
      int d = dc * 8 + e;
      float4 a0 = *(const float4*)&agT[d][0];
      float4 a1 = *(const float4*)&agT[d][4];
      sc[0] += a0.x * qv; sc[1] += a0.y * qv; sc[2] += a0.z * qv; sc[3] += a0.w * qv;
      sc[4] += a1.x * qv; sc[5] += a1.y * qv; sc[6] += a1.z * qv; sc[7] += a1.w * qv;
    }
  }
  float m = sc[0];
#pragma unroll
  for (int p = 1; p < 8; ++p) m = fmaxf(m, sc[p]);
  float wsum = 0.f, wgt[8];
#pragma unroll
  for (int p = 0; p < 8; ++p) { wgt[p] = __expf(sc[p] - m); wsum += wgt[p]; }
  float inv = 1.0f / wsum;
  int b = bh >> 4, h = bh & 15;
  bf16x8 o8;
#pragma unroll
  for (int p = 0; p < 8; ++p) o8[p] = (bf16)(wgt[p] * inv);
  *(bf16x8*)&P2[((size_t)(b * SEQ + t)) * HP + h * 8] = o8;
}

extern "C" void kernel_launch(void* const* d_in, const int* in_sizes, int n_in,
                              void* d_out, int out_size, void* d_ws, size_t ws_size,
                              hipStream_t stream) {
  const float* x    = (const float*)d_in[0];   // [4,4096,1024] fp32
  const float* Wqkv = (const float*)d_in[1];   // [1024,3072]   fp32
  const float* Wo   = (const float*)d_in[2];   // [1024,1024]   fp32
  const float* bo   = (const float*)d_in[3];   // [1024]        fp32
  float* out = (float*)d_out;                  // [4,4096,1024] fp32

  char* ws = (char*)d_ws;
  bf16* WqkvT = (bf16*)ws;                                   ws += (size_t)QKV_N * DIMV * 2;
  bf16* WoT   = (bf16*)ws;                                   ws += (size_t)DIMV * DIMV * 2;
  bf16* qkv   = (bf16*)ws;                                   ws += 3 * QKVSZ * 2;
  char* wsu   = ws;                                          ws += (size_t)M_TOTAL * DIMV * 2;
  bf16*  xb    = (bf16*)wsu;
  bf16*  P2    = (bf16*)wsu;                                  // 4 MB (after xb dead)
  bf16*  W2T   = (bf16*)(wsu + (size_t)M_TOTAL * HP * 2);     // 1 MB
  float* agent = (float*)ws;                                 ws += 512 * 64 * 4;
  float* pm    = (float*)ws;                                 ws += BH * TCH * 8 * 4;
  float* pl    = (float*)ws;                                 ws += BH * TCH * 8 * 4;
  float* pva   = (float*)ws;                                 ws += (size_t)BH * TCH * 8 * DH * 4;
  float* vag   = (float*)ws;                                 ws += 512 * 64 * 4;

  const bf16* qp = qkv;
  const bf16* kp = qkv + QKVSZ;
  const bf16* vp = qkv + 2 * QKVSZ;

  // agent accumulated by GEMM1-epilogue atomics -> zero it first
  hipMemsetAsync(agent, 0, 512 * 64 * 4, stream);

  // fused prep: convert_x (8192 blocks) + Wqkv transpose (3072) + Wo (1024)
  prep<<<12288, 256, 0, stream>>>(x, xb, Wqkv, WqkvT, Wo, WoT);

  // GEMM1: qkv = x @ Wqkv (split planes) + fused q pooling sums
  gemm1_qkv<<<768, 512, 0, stream>>>(xb, WqkvT, qkv, agent);

  p2_build<<<dim3(SEQ / 256, BH), 256, 0, stream>>>(qp, agent, P2);
  stage1_fused<<<dim3(TCH, BH), 256, 0, stream>>>(kp, vp, agent, pm, pl, pva);
  combine_vag<<<BH, 256, 0, stream>>>(pm, pl, pva, vag);
  w2_build<<<dim3(DIMV / 16, BATCH), 256, 0, stream>>>(vag, WoT, W2T);

  // GEMM2: out = P2 @ W2T(batched) + bo   (fp32 out, K=128, 256 blocks)
  gemm2_256<<<256, 512, 0, stream>>>(P2, W2T, out, bo);
}

// Round 7
// 309.311 us; speedup vs baseline: 1.0581x; 1.0271x over previous
//
#include <hip/hip_runtime.h>
#include <hip/hip_bf16.h>
#include <stdint.h>

typedef __bf16 bf16;
typedef __attribute__((ext_vector_type(8))) __bf16 bf16x8;
typedef __attribute__((ext_vector_type(4))) float f32x4;
typedef __attribute__((ext_vector_type(4))) unsigned int u32x4;

#define NH 16
#define DH 64
#define POOL 8
#define BATCH 4
#define SEQ 4096
#define DIMV 1024
#define QKV_N (3*DIMV)
#define M_TOTAL (BATCH*SEQ)
#define SCALE_F 0.125f
// agent buffer holds SUMS over 512 t (from GEMM1-epilogue atomics);
// consumers fold mean (1/512) into the pre-softmax dot: exact.
#define AGS_F (SCALE_F / 512.0f)
#define BH (BATCH*NH)              // 64
#define QKVSZ ((size_t)BH*SEQ*DH)  // elems per q/k/v plane
#define TCH 16                     // t-split chunks for stage1
#define TCL (SEQ/TCH)              // 256 t per chunk
#define HP 128                     // h*p combined dim for P2/W2

#define AS1(p) ((const __attribute__((address_space(1))) void*)(p))
#define AS3(p) ((__attribute__((address_space(3))) void*)(p))
typedef const __attribute__((address_space(3))) char* lds_cp;

// ---------------- fused prep: x->bf16 convert + both weight transposes ------
// block ranges: [0,8192) convert_x; [8192,11264) Wqkv transpose; rest Wo.
__global__ void prep(const float* __restrict__ x, bf16* __restrict__ xb,
                     const float* __restrict__ Wqkv, bf16* __restrict__ WqkvT,
                     const float* __restrict__ Wo, bf16* __restrict__ WoT) {
  __shared__ float tile[32][33];
  const int b = blockIdx.x;
  if (b < 8192) {
    size_t i = ((size_t)b * 256 + threadIdx.x) * 8;
    float4 f0 = *(const float4*)(x + i);
    float4 f1 = *(const float4*)(x + i + 4);
    bf16x8 o;
    o[0] = (bf16)f0.x; o[1] = (bf16)f0.y; o[2] = (bf16)f0.z; o[3] = (bf16)f0.w;
    o[4] = (bf16)f1.x; o[5] = (bf16)f1.y; o[6] = (bf16)f1.z; o[7] = (bf16)f1.w;
    *(bf16x8*)(xb + i) = o;
    return;
  }
  const float* in; bf16* out; int C, bx, by;
  if (b < 8192 + 3072) { int bb = b - 8192;  in = Wqkv; out = WqkvT; C = QKV_N; bx = bb % 96; by = bb / 96; }
  else                 { int bb = b - 11264; in = Wo;   out = WoT;   C = DIMV;  bx = bb % 32; by = bb / 32; }
  const int R = DIMV;
  int c0 = bx * 32, r0 = by * 32;
  int tx = threadIdx.x & 31, ty = threadIdx.x >> 5;
  for (int i = ty; i < 32; i += 8)
    tile[i][tx] = in[(size_t)(r0 + i) * C + c0 + tx];
  __syncthreads();
  for (int i = ty; i < 32; i += 8)
    out[(size_t)(c0 + i) * R + r0 + tx] = (bf16)tile[tx][i];
}

// ============================================================================
// GEMM1: 256x256 tile, BK=64, 8 waves, 8-phase schedule.  BYTE-IDENTICAL to
// the R1 kernel (verified: 106.5us, MfmaUtil 41%, bank conflicts 0, passed).
// R2/R3 counted-lgkm restructures both lost to this; 1 block/CU (128KB LDS)
// is structural: 128 acc VGPR/thread forbids 2 blocks at this tile.
// ============================================================================
__global__ __launch_bounds__(512, 2)
void gemm1_qkv(const bf16* __restrict__ A, const bf16* __restrict__ B,
               bf16* __restrict__ qkvOut, float* __restrict__ agentSum) {
  constexpr int K1 = DIMV;       // 1024
  constexpr int NI = K1 / 128;   // 8 pipeline iterations (2 K-tiles each)

  __shared__ __align__(16) bf16 LA[2][2][8192];   // [buf][half][128*64]
  __shared__ __align__(16) bf16 LB[2][2][8192];

  const int tid  = threadIdx.x;
  const int w    = tid >> 6;
  const int lane = tid & 63;
  const int wm = (w >> 2) * 128;         // 2 M-waves x 4 N-waves
  const int wn = (w & 3) * 64;

  // bijective XCD swizzle (768 % 8 == 0)
  const int bid = blockIdx.x;
  const int swz = (bid & 7) * 96 + (bid >> 3);
  const int m0 = (swz / 12) * 256;
  const int n0 = (swz % 12) * 256;

  // staging: thread t covers (row rT + 64*e + 128*half, 16B slot t&7);
  // source column pre-swizzled so linear LDS dest realizes slot^(row&7).
  const int rT  = tid >> 3;
  const int csT = (((tid & 7) ^ (rT & 7)) << 3);
  const bf16* Ag = A + (size_t)(m0 + rT) * K1 + csT;
  const bf16* Bg = B + (size_t)(n0 + rT) * K1 + csT;

  // ds_read lane constants: row rA within 16-row frag, k-group C, xor rA&7
  const int rA = lane & 15, C = lane >> 4, xr = rA & 7;
  const unsigned s0 = (unsigned)(((0 * 4 + C) ^ xr) << 4);   // ks=0 slot byte
  const unsigned s1 = (unsigned)(((1 * 4 + C) ^ xr) << 4);   // ks=1 slot byte
  const unsigned aoff = (unsigned)((wm + rA) << 7);          // folds half+row
  const unsigned boff = (unsigned)((wn + rA) << 7);

  f32x4 acc[8][4] = {};
  u32x4 aR[4][2], bR[4][2];

#define STG(arr, Gp, half, kofs) do {                                         \
    const bf16* _s = (Gp) + (size_t)((half) * 128) * K1 + (kofs);             \
    char* _d = (char*)&arr[half][0] + (w << 10);                              \
    __builtin_amdgcn_global_load_lds(AS1(_s), AS3(_d), 16, 0, 0);             \
    __builtin_amdgcn_global_load_lds(AS1(_s + 64 * K1), AS3(_d + 8192), 16, 0, 0); \
  } while (0)

#define DSR0(d, p)    asm volatile("ds_read_b128 %0, %1" : "=v"(d) : "v"(p))
#define DSR(d, p, o)  asm volatile("ds_read_b128 %0, %1 offset:" o : "=v"(d) : "v"(p))

#define READS_A(LAb, qm) do {                                                 \
    lds_cp _p0 = (lds_cp)(const char*)&LAb[0][0] + aoff + s0 + (qm) * 8192;   \
    lds_cp _p1 = (lds_cp)(const char*)&LAb[0][0] + aoff + s1 + (qm) * 8192;   \
    DSR0(aR[0][0], _p0); DSR(aR[1][0], _p0, "2048");                          \
    DSR(aR[2][0], _p0, "4096"); DSR(aR[3][0], _p0, "6144");                   \
    DSR0(aR[0][1], _p1); DSR(aR[1][1], _p1, "2048");                          \
    DSR(aR[2][1], _p1, "4096"); DSR(aR[3][1], _p1, "6144");                   \
  } while (0)

#define READS_B01(LBb) do {                                                   \
    lds_cp _p0 = (lds_cp)(const char*)&LBb[0][0] + boff + s0;                 \
    lds_cp _p1 = (lds_cp)(const char*)&LBb[0][0] + boff + s1;                 \
    DSR0(bR[0][0], _p0); DSR(bR[1][0], _p0, "2048");                          \
    DSR0(bR[0][1], _p1); DSR(bR[1][1], _p1, "2048");                          \
  } while (0)

#define READS_B23(LBb) do {                                                   \
    lds_cp _p0 = (lds_cp)(const char*)&LBb[0][0] + boff + s0;                 \
    lds_cp _p1 = (lds_cp)(const char*)&LBb[0][0] + boff + s1;                 \
    DSR(bR[2][0], _p0, "4096"); DSR(bR[3][0], _p0, "6144");                   \
    DSR(bR[2][1], _p1, "4096"); DSR(bR[3][1], _p1, "6144");                   \
  } while (0)

#define MFMA_Q(qm, qn) do {                                                   \
    asm volatile("s_waitcnt lgkmcnt(0)");                                     \
    __builtin_amdgcn_sched_barrier(0);                                        \
    __builtin_amdgcn_s_setprio(1);                                            \
    _Pragma("unroll")                                                         \
    for (int il = 0; il < 4; ++il)                                            \
      _Pragma("unroll")                                                       \
      for (int jj = 0; jj < 2; ++jj) {                                        \
        f32x4& ac = acc[(qm) * 4 + il][(qn) * 2 + jj];                        \
        ac = __builtin_amdgcn_mfma_f32_16x16x32_bf16(                         \
            __builtin_bit_cast(bf16x8, aR[il][0]),                            \
            __builtin_bit_cast(bf16x8, bR[(qn) * 2 + jj][0]), ac, 0, 0, 0);   \
        ac = __builtin_amdgcn_mfma_f32_16x16x32_bf16(                         \
            __builtin_bit_cast(bf16x8, aR[il][1]),                            \
            __builtin_bit_cast(bf16x8, bR[(qn) * 2 + jj][1]), ac, 0, 0, 0);   \
      }                                                                       \
    __builtin_amdgcn_s_setprio(0);                                            \
    __builtin_amdgcn_sched_barrier(0);                                        \
  } while (0)

#define BAR __builtin_amdgcn_s_barrier()

  // prologue: tile0 (A+B) -> buf0; tile1 B -> buf1   (12 issues)
  STG(LA[0], Ag, 0, 0); STG(LA[0], Ag, 1, 0);
  STG(LB[0], Bg, 0, 0); STG(LB[0], Bg, 1, 0);
  STG(LB[1], Bg, 0, 64); STG(LB[1], Bg, 1, 64);
  asm volatile("s_waitcnt vmcnt(4)");    // buf0 tile landed; buf1 B in flight
  __builtin_amdgcn_sched_barrier(0);
  BAR;

  int kk = 0;
  for (int i = 0; i < NI - 1; ++i, kk += 128) {
    // ---- phases 1-4: consume buf0 (tile 2i) ----
    READS_A(LA[0], 0); READS_B01(LB[0]);
    STG(LA[1], Ag, 0, kk + 64);          // ph1: buf1.A0 <- tile 2i+1
    BAR; MFMA_Q(0, 0); BAR;
    READS_B23(LB[0]);
    STG(LA[1], Ag, 1, kk + 64);          // ph2: buf1.A1 <- tile 2i+1
    BAR; MFMA_Q(0, 1); BAR;
    READS_A(LA[0], 1);
    STG(LB[0], Bg, 0, kk + 128);         // ph3: buf0.B0 <- tile 2i+2
    BAR; MFMA_Q(1, 0); BAR;
    STG(LB[0], Bg, 1, kk + 128);         // ph4: buf0.B1 <- tile 2i+2
    BAR; MFMA_Q(1, 1);
    asm volatile("s_waitcnt vmcnt(4)");  // buf1 tile 2i+1 landed
    __builtin_amdgcn_sched_barrier(0);
    BAR;
    // ---- phases 5-8: consume buf1 (tile 2i+1) ----
    READS_A(LA[1], 0); READS_B01(LB[1]);
    STG(LA[0], Ag, 0, kk + 128);         // ph5: buf0.A0 <- tile 2i+2
    BAR; MFMA_Q(0, 0); BAR;
    READS_B23(LB[1]);
    STG(LA[0], Ag, 1, kk + 128);         // ph6: buf0.A1 <- tile 2i+2
    BAR; MFMA_Q(0, 1); BAR;
    READS_A(LA[1], 1);
    STG(LB[1], Bg, 0, kk + 192);         // ph7: buf1.B0 <- tile 2i+3
    BAR; MFMA_Q(1, 0); BAR;
    STG(LB[1], Bg, 1, kk + 192);         // ph8: buf1.B1 <- tile 2i+3
    BAR; MFMA_Q(1, 1);
    asm volatile("s_waitcnt vmcnt(4)");  // buf0 tile 2i+2 landed
    __builtin_amdgcn_sched_barrier(0);
    BAR;
  }
  // ---- tail iteration: buf0 = tile NT-2, buf1 = tile NT-1 ----
  READS_A(LA[0], 0); READS_B01(LB[0]);
  STG(LA[1], Ag, 0, kk + 64);            // last A halves of tile NT-1
  BAR; MFMA_Q(0, 0); BAR;
  READS_B23(LB[0]);
  STG(LA[1], Ag, 1, kk + 64);
  BAR; MFMA_Q(0, 1); BAR;
  READS_A(LA[0], 1);
  BAR; MFMA_Q(1, 0); BAR;
  MFMA_Q(1, 1);
  asm volatile("s_waitcnt vmcnt(0)");    // drain: buf1 tile NT-1 landed
  __builtin_amdgcn_sched_barrier(0);
  BAR;
  READS_A(LA[1], 0); READS_B01(LB[1]);
  BAR; MFMA_Q(0, 0); BAR;
  READS_B23(LB[1]);
  BAR; MFMA_Q(0, 1); BAR;
  READS_A(LA[1], 1);
  BAR; MFMA_Q(1, 0); BAR;
  MFMA_Q(1, 1);

#undef STG
#undef DSR0
#undef DSR
#undef READS_A
#undef READS_B01
#undef READS_B23
#undef MFMA_Q
#undef BAR

  // ---- epilogue: scatter to q/k/v planes (C/D layout col=lane&15,
  //      row=(lane>>4)*4+r); wave owns rows [m0+wm,+128), cols = one 64-d head.
  const int cr = (lane >> 4) * 4;
  const int cc = lane & 15;
  const int ncol  = n0 + wn;             // multiple of 64 -> single (plane,head)
  const int which = ncol >> 10;
  const int hh    = (ncol >> 6) & 15;
  const int rowb  = m0 + wm;
  const int bb_   = rowb >> 12;
  const int tb    = rowb & 4095;
  bf16* Cp = qkvOut + (size_t)which * QKVSZ + (size_t)(bb_ * NH + hh) * SEQ * DH;
#pragma unroll
  for (int i = 0; i < 8; ++i)
#pragma unroll
    for (int j = 0; j < 4; ++j)
#pragma unroll
      for (int r = 0; r < 4; ++r)
        Cp[(size_t)(tb + i * 16 + cr + r) * DH + j * 16 + cc] = (bf16)acc[i][j][r];

  // fused agent pooling (q plane only): all 128 rows lie in one 512-t bucket.
  if (which == 0) {
    const int pp = tb >> 9;
    float* ag = agentSum + ((size_t)(bb_ * NH + hh) * POOL + pp) * DH;
#pragma unroll
    for (int j = 0; j < 4; ++j) {
      float s = 0.f;
#pragma unroll
      for (int i = 0; i < 8; ++i)
        s += acc[i][j][0] + acc[i][j][1] + acc[i][j][2] + acc[i][j][3];
      s += __shfl_xor(s, 16);
      s += __shfl_xor(s, 32);
      if (lane < 16) atomicAdd(&ag[j * 16 + lane], s);
    }
  }
}

// ============================================================================
// GEMM2: out = P2 @ W2T(batched)^T + bo.  256x256 tile, K=128 (2 K-tiles,
// R1-verified prologue+tail path).  Grid 256 = 1 block/CU.
// ============================================================================
__global__ __launch_bounds__(512, 2)
void gemm2_256(const bf16* __restrict__ A, const bf16* __restrict__ B,
               float* __restrict__ Out, const float* __restrict__ bias) {
  constexpr int K2 = HP;   // 128

  __shared__ __align__(16) bf16 LA[2][2][8192];
  __shared__ __align__(16) bf16 LB[2][2][8192];

  const int tid  = threadIdx.x;
  const int w    = tid >> 6;
  const int lane = tid & 63;
  const int wm = (w >> 2) * 128;
  const int wn = (w & 3) * 64;

  const int bid = blockIdx.x;
  const int swz = (bid & 7) * 32 + (bid >> 3);   // bijective, 256 % 8 == 0
  const int m0 = (swz >> 2) * 256;
  const int n0 = (swz & 3) * 256;

  const int rT  = tid >> 3;
  const int csT = (((tid & 7) ^ (rT & 7)) << 3);
  const bf16* Ag = A + (size_t)(m0 + rT) * K2 + csT;
  // B = W2T [batch][n][hp]; 256 | 4096 -> whole M-tile in one batch
  const bf16* Bg = B + ((size_t)(m0 >> 12) * DIMV + n0 + rT) * K2 + csT;

  const int rA = lane & 15, C = lane >> 4, xr = rA & 7;
  const unsigned s0 = (unsigned)(((0 * 4 + C) ^ xr) << 4);
  const unsigned s1 = (unsigned)(((1 * 4 + C) ^ xr) << 4);
  const unsigned aoff = (unsigned)((wm + rA) << 7);
  const unsigned boff = (unsigned)((wn + rA) << 7);

  f32x4 acc[8][4] = {};
  u32x4 aR[4][2], bR[4][2];

#define STG(arr, Gp, half, kofs) do {                                         \
    const bf16* _s = (Gp) + (size_t)((half) * 128) * K2 + (kofs);             \
    char* _d = (char*)&arr[half][0] + (w << 10);                              \
    __builtin_amdgcn_global_load_lds(AS1(_s), AS3(_d), 16, 0, 0);             \
    __builtin_amdgcn_global_load_lds(AS1(_s + 64 * K2), AS3(_d + 8192), 16, 0, 0); \
  } while (0)

#define DSR0(d, p)    asm volatile("ds_read_b128 %0, %1" : "=v"(d) : "v"(p))
#define DSR(d, p, o)  asm volatile("ds_read_b128 %0, %1 offset:" o : "=v"(d) : "v"(p))

#define READS_A(LAb, qm) do {                                                 \
    lds_cp _p0 = (lds_cp)(const char*)&LAb[0][0] + aoff + s0 + (qm) * 8192;   \
    lds_cp _p1 = (lds_cp)(const char*)&LAb[0][0] + aoff + s1 + (qm) * 8192;   \
    DSR0(aR[0][0], _p0); DSR(aR[1][0], _p0, "2048");                          \
    DSR(aR[2][0], _p0, "4096"); DSR(aR[3][0], _p0, "6144");                   \
    DSR0(aR[0][1], _p1); DSR(aR[1][1], _p1, "2048");                          \
    DSR(aR[2][1], _p1, "4096"); DSR(aR[3][1], _p1, "6144");                   \
  } while (0)

#define READS_B01(LBb) do {                                                   \
    lds_cp _p0 = (lds_cp)(const char*)&LBb[0][0] + boff + s0;                 \
    lds_cp _p1 = (lds_cp)(const char*)&LBb[0][0] + boff + s1;                 \
    DSR0(bR[0][0], _p0); DSR(bR[1][0], _p0, "2048");                          \
    DSR0(bR[0][1], _p1); DSR(bR[1][1], _p1, "2048");                          \
  } while (0)

#define READS_B23(LBb) do {                                                   \
    lds_cp _p0 = (lds_cp)(const char*)&LBb[0][0] + boff + s0;                 \
    lds_cp _p1 = (lds_cp)(const char*)&LBb[0][0] + boff + s1;                 \
    DSR(bR[2][0], _p0, "4096"); DSR(bR[3][0], _p0, "6144");                   \
    DSR(bR[2][1], _p1, "4096"); DSR(bR[3][1], _p1, "6144");                   \
  } while (0)

#define MFMA_Q(qm, qn) do {                                                   \
    asm volatile("s_waitcnt lgkmcnt(0)");                                     \
    __builtin_amdgcn_sched_barrier(0);                                        \
    __builtin_amdgcn_s_setprio(1);                                            \
    _Pragma("unroll")                                                         \
    for (int il = 0; il < 4; ++il)                                            \
      _Pragma("unroll")                                                       \
      for (int jj = 0; jj < 2; ++jj) {                                        \
        f32x4& ac = acc[(qm) * 4 + il][(qn) * 2 + jj];                        \
        ac = __builtin_amdgcn_mfma_f32_16x16x32_bf16(                         \
            __builtin_bit_cast(bf16x8, aR[il][0]),                            \
            __builtin_bit_cast(bf16x8, bR[(qn) * 2 + jj][0]), ac, 0, 0, 0);   \
        ac = __builtin_amdgcn_mfma_f32_16x16x32_bf16(                         \
            __builtin_bit_cast(bf16x8, aR[il][1]),                            \
            __builtin_bit_cast(bf16x8, bR[(qn) * 2 + jj][1]), ac, 0, 0, 0);   \
      }                                                                       \
    __builtin_amdgcn_s_setprio(0);                                            \
    __builtin_amdgcn_sched_barrier(0);                                        \
  } while (0)

#define BAR __builtin_amdgcn_s_barrier()

  // prologue (R1 pattern): tile0 A+B -> buf0; tile1 B -> buf1
  STG(LA[0], Ag, 0, 0); STG(LA[0], Ag, 1, 0);
  STG(LB[0], Bg, 0, 0); STG(LB[0], Bg, 1, 0);
  STG(LB[1], Bg, 0, 64); STG(LB[1], Bg, 1, 64);
  asm volatile("s_waitcnt vmcnt(4)");
  __builtin_amdgcn_sched_barrier(0);
  BAR;

  // tile 0 (R1 tail structure, kk = 0)
  READS_A(LA[0], 0); READS_B01(LB[0]);
  STG(LA[1], Ag, 0, 64);
  BAR; MFMA_Q(0, 0); BAR;
  READS_B23(LB[0]);
  STG(LA[1], Ag, 1, 64);
  BAR; MFMA_Q(0, 1); BAR;
  READS_A(LA[0], 1);
  BAR; MFMA_Q(1, 0); BAR;
  MFMA_Q(1, 1);
  asm volatile("s_waitcnt vmcnt(0)");
  __builtin_amdgcn_sched_barrier(0);
  BAR;
  // tile 1
  READS_A(LA[1], 0); READS_B01(LB[1]);
  BAR; MFMA_Q(0, 0); BAR;
  READS_B23(LB[1]);
  BAR; MFMA_Q(0, 1); BAR;
  READS_A(LA[1], 1);
  BAR; MFMA_Q(1, 0); BAR;
  MFMA_Q(1, 1);

#undef STG
#undef DSR0
#undef DSR
#undef READS_A
#undef READS_B01
#undef READS_B23
#undef MFMA_Q
#undef BAR

  // epilogue: fp32 row-major + bias
  const int cr = (lane >> 4) * 4;
  const int cc = lane & 15;
  const int rowb = m0 + wm;
  float bb4[4];
#pragma unroll
  for (int j = 0; j < 4; ++j) bb4[j] = bias[n0 + wn + j * 16 + cc];
#pragma unroll
  for (int i = 0; i < 8; ++i)
#pragma unroll
    for (int j = 0; j < 4; ++j) {
      const int col = n0 + wn + j * 16 + cc;
#pragma unroll
      for (int r = 0; r < 4; ++r)
        Out[(size_t)(rowb + i * 16 + cr + r) * DIMV + col] = acc[i][j][r] + bb4[j];
    }
}

// ============================================================================
// attn_mid: fused p2_build + stage1.  One block per (tc, bh); 256 threads.
//   Phase 1 (shared agT stream): thread owns row t = t0+tid; loads q-row AND
//   k-row; per d: 2 LDS b128 reads of agT feed 16 FMAs (8 q + 8 k) -- halves
//   the LDS-pipe cost vs two separate kernels (was the modeled bottleneck).
//   q-scores -> softmax over p -> P2 (bf16).  k-scores -> chunk max/sum ->
//   se + pm/pl (partial softmax, combined later).
//   Phase 2 (PV partial): wave w owns p={2w,2w+1}; lanes=(to 0..7, dg 0..7);
//   V read with 1KB/wave coalescing at 4 reads/elem (was 8, 512B); to-reduce
//   via 3x shfl_xor (8/16/32) in-register -- no pr[] LDS, no extra barrier.
// ============================================================================
__global__ __launch_bounds__(256)
void attn_mid(const bf16* __restrict__ q, const bf16* __restrict__ k,
              const bf16* __restrict__ v, const float* __restrict__ agentSum,
              bf16* __restrict__ P2,
              float* __restrict__ pm, float* __restrict__ pl,
              float* __restrict__ pva) {
  const int tc = blockIdx.x, bh = blockIdx.y;
  const int tid = threadIdx.x;
  const int t0 = tc * TCL;

  __shared__ float agT[64][8];           // [d][p], scaled by SCALE/512
  __shared__ float se[TCL][9];           // exp(sck-m), pad to 9
  __shared__ float rm[4][8], rl[4][8];

  for (int i = tid; i < 512; i += 256) {
    int p = i >> 6, d = i & 63;
    agT[d][p] = agentSum[(size_t)bh * 512 + i] * AGS_F;
  }
  __syncthreads();

  // ---- phase 1: q-row and k-row share the agT read stream ----
  const bf16* qrow = q + ((size_t)bh * SEQ + t0 + tid) * DH;
  const bf16* krow = k + ((size_t)bh * SEQ + t0 + tid) * DH;
  float scq[8] = {}, sck[8] = {};
#pragma unroll
  for (int dc = 0; dc < 8; ++dc) {
    bf16x8 q8 = *(const bf16x8*)(qrow + dc * 8);
    bf16x8 k8 = *(const bf16x8*)(krow + dc * 8);
#pragma unroll
    for (int e = 0; e < 8; ++e) {
      float qv = (float)q8[e];
      float kv = (float)k8[e];
      int d = dc * 8 + e;
      float4 a0 = *(const float4*)&agT[d][0];
      float4 a1 = *(const float4*)&agT[d][4];
      scq[0] += a0.x * qv; scq[1] += a0.y * qv; scq[2] += a0.z * qv; scq[3] += a0.w * qv;
      scq[4] += a1.x * qv; scq[5] += a1.y * qv; scq[6] += a1.z * qv; scq[7] += a1.w * qv;
      sck[0] += a0.x * kv; sck[1] += a0.y * kv; sck[2] += a0.z * kv; sck[3] += a0.w * kv;
      sck[4] += a1.x * kv; sck[5] += a1.y * kv; sck[6] += a1.z * kv; sck[7] += a1.w * kv;
    }
  }

  // P2: per-row softmax over p (independent of k path)
  {
    float m = scq[0];
#pragma unroll
    for (int p = 1; p < 8; ++p) m = fmaxf(m, scq[p]);
    float wsum = 0.f, wgt[8];
#pragma unroll
    for (int p = 0; p < 8; ++p) { wgt[p] = __expf(scq[p] - m); wsum += wgt[p]; }
    float inv = 1.0f / wsum;
    int b = bh >> 4, h = bh & 15;
    bf16x8 o8;
#pragma unroll
    for (int p = 0; p < 8; ++p) o8[p] = (bf16)(wgt[p] * inv);
    *(bf16x8*)&P2[((size_t)(b * SEQ + t0 + tid)) * HP + h * 8] = o8;
  }

  // k path: chunk max
  float mx[8];
#pragma unroll
  for (int p = 0; p < 8; ++p) mx[p] = sck[p];
#pragma unroll
  for (int o = 32; o; o >>= 1)
#pragma unroll
    for (int p = 0; p < 8; ++p) mx[p] = fmaxf(mx[p], __shfl_xor(mx[p], o));
  if ((tid & 63) == 0)
#pragma unroll
    for (int p = 0; p < 8; ++p) rm[tid >> 6][p] = mx[p];
  __syncthreads();
  float m[8];
#pragma unroll
  for (int p = 0; p < 8; ++p)
    m[p] = fmaxf(fmaxf(rm[0][p], rm[1][p]), fmaxf(rm[2][p], rm[3][p]));

  float sl[8];
#pragma unroll
  for (int p = 0; p < 8; ++p) {
    float e = __expf(sck[p] - m[p]);
    se[tid][p] = e;
    sl[p] = e;
  }
#pragma unroll
  for (int o = 32; o; o >>= 1)
#pragma unroll
    for (int p = 0; p < 8; ++p) sl[p] += __shfl_xor(sl[p], o);
  if ((tid & 63) == 0)
#pragma unroll
    for (int p = 0; p < 8; ++p) rl[tid >> 6][p] = sl[p];
  __syncthreads();
  if (tid < 8) {
    float l = rl[0][tid] + rl[1][tid] + rl[2][tid] + rl[3][tid];
    pm[(size_t)(bh * TCH + tc) * 8 + tid] = m[tid];
    pl[(size_t)(bh * TCH + tc) * 8 + tid] = l;
  }
  __syncthreads();   // se complete for phase 2

  // ---- phase 2: pva[p][d] = sum_t se[t][p]*v[t][d] ----
  const int lane = tid & 63;
  const int wv = tid >> 6;          // wave id: p = {2wv, 2wv+1}
  const int dg = lane & 7;          // d-octet
  const int to = lane >> 3;         // 0..7 t-offset (full range in-wave)
  const int p0 = wv * 2;
  const bf16* vb = v + ((size_t)bh * SEQ + t0 + to) * DH + dg * 8;
  float a0[8] = {}, a1[8] = {};
  for (int tl = to; tl < TCL; tl += 8) {
    bf16x8 v8 = *(const bf16x8*)(vb + (size_t)(tl - to) * DH);
    float w0 = se[tl][p0];
    float w1 = se[tl][p0 + 1];
#pragma unroll
    for (int e = 0; e < 8; ++e) {
      float vf = (float)v8[e];
      a0[e] += w0 * vf;
      a1[e] += w1 * vf;
    }
  }
  // reduce over to (lane bits 3,4,5)
#pragma unroll
  for (int o = 8; o <= 32; o <<= 1) {
#pragma unroll
    for (int e = 0; e < 8; ++e) {
      a0[e] += __shfl_xor(a0[e], o);
      a1[e] += __shfl_xor(a1[e], o);
    }
  }
  if (to == 0) {   // lanes 0..7 hold sums
    float* o0 = pva + ((size_t)(bh * TCH + tc) * 8 + p0) * DH + dg * 8;
    float* o1 = o0 + DH;
#pragma unroll
    for (int e = 0; e < 8; ++e) { o0[e] = a0[e]; o1[e] = a1[e]; }
  }
}

// ---------------- combine chunk partials -> v_agent[bh][p][d] ----------------
__global__ void combine_vag(const float* __restrict__ pm, const float* __restrict__ pl,
                            const float* __restrict__ pva, float* __restrict__ vag) {
  int bh = blockIdx.x;
#pragma unroll
  for (int e = threadIdx.x; e < 512; e += 256) {
    int p = e >> 6, d = e & 63;
    float M = -1e30f;
#pragma unroll
    for (int tc = 0; tc < TCH; ++tc)
      M = fmaxf(M, pm[(size_t)(bh * TCH + tc) * 8 + p]);
    float L = 0.f, acc = 0.f;
#pragma unroll
    for (int tc = 0; tc < TCH; ++tc) {
      float w = __expf(pm[(size_t)(bh * TCH + tc) * 8 + p] - M);
      L   += w * pl[(size_t)(bh * TCH + tc) * 8 + p];
      acc += w * pva[((size_t)(bh * TCH + tc) * 8 + p) * DH + d];
    }
    vag[(size_t)bh * 512 + e] = acc / L;
  }
}

// ---- W2T[b][n][hp] = sum_d vag[b][hp][d] * WoT[n][h*64+d]  (bf16 out) ----
__global__ void w2_build(const float* __restrict__ vag, const bf16* __restrict__ WoT,
                         bf16* __restrict__ W2T) {
  int b = blockIdx.y;
  int n = blockIdx.x * 16 + (threadIdx.x & 15);
  int h = threadIdx.x >> 4;
  __shared__ float vg[128][65];
  for (int i = threadIdx.x; i < 128 * 64; i += 256)
    vg[i >> 6][i & 63] = vag[(size_t)b * 128 * 64 + i];
  __syncthreads();
  float acc[8] = {};
  const bf16* wrow = WoT + (size_t)n * DIMV + h * 64;
#pragma unroll
  for (int dv = 0; dv < 8; ++dv) {
    bf16x8 wv = *(const bf16x8*)(wrow + dv * 8);
#pragma unroll
    for (int e = 0; e < 8; ++e) {
      float wf = (float)wv[e];
      int d = dv * 8 + e;
#pragma unroll
      for (int p = 0; p < 8; ++p) acc[p] += vg[h * 8 + p][d] * wf;
    }
  }
  bf16x8 o;
#pragma unroll
  for (int p = 0; p < 8; ++p) o[p] = (bf16)acc[p];
  *(bf16x8*)&W2T[((size_t)b * DIMV + n) * HP + h * 8] = o;
}

extern "C" void kernel_launch(void* const* d_in, const int* in_sizes, int n_in,
                              void* d_out, int out_size, void* d_ws, size_t ws_size,
                              hipStream_t stream) {
  const float* x    = (const float*)d_in[0];   // [4,4096,1024] fp32
  const float* Wqkv = (const float*)d_in[1];   // [1024,3072]   fp32
  const float* Wo   = (const float*)d_in[2];   // [1024,1024]   fp32
  const float* bo   = (const float*)d_in[3];   // [1024]        fp32
  float* out = (float*)d_out;                  // [4,4096,1024] fp32

  char* ws = (char*)d_ws;
  bf16* WqkvT = (bf16*)ws;                                   ws += (size_t)QKV_N * DIMV * 2;
  bf16* WoT   = (bf16*)ws;                                   ws += (size_t)DIMV * DIMV * 2;
  bf16* qkv   = (bf16*)ws;                                   ws += 3 * QKVSZ * 2;
  char* wsu   = ws;                                          ws += (size_t)M_TOTAL * DIMV * 2;
  bf16*  xb    = (bf16*)wsu;
  bf16*  P2    = (bf16*)wsu;                                  // 4 MB (after xb dead)
  bf16*  W2T   = (bf16*)(wsu + (size_t)M_TOTAL * HP * 2);     // 1 MB
  float* agent = (float*)ws;                                 ws += 512 * 64 * 4;
  float* pm    = (float*)ws;                                 ws += BH * TCH * 8 * 4;
  float* pl    = (float*)ws;                                 ws += BH * TCH * 8 * 4;
  float* pva   = (float*)ws;                                 ws += (size_t)BH * TCH * 8 * DH * 4;
  float* vag   = (float*)ws;                                 ws += 512 * 64 * 4;

  const bf16* qp = qkv;
  const bf16* kp = qkv + QKVSZ;
  const bf16* vp = qkv + 2 * QKVSZ;

  // agent accumulated by GEMM1-epilogue atomics -> zero it first
  hipMemsetAsync(agent, 0, 512 * 64 * 4, stream);

  // fused prep: convert_x (8192 blocks) + Wqkv transpose (3072) + Wo (1024)
  prep<<<12288, 256, 0, stream>>>(x, xb, Wqkv, WqkvT, Wo, WoT);

  // GEMM1: qkv = x @ Wqkv (split planes) + fused q pooling sums
  gemm1_qkv<<<768, 512, 0, stream>>>(xb, WqkvT, qkv, agent);

  // fused p2_build + stage1
  attn_mid<<<dim3(TCH, BH), 256, 0, stream>>>(qp, kp, vp, agent, P2, pm, pl, pva);

  combine_vag<<<BH, 256, 0, stream>>>(pm, pl, pva, vag);
  w2_build<<<dim3(DIMV / 16, BATCH), 256, 0, stream>>>(vag, WoT, W2T);

  // GEMM2: out = P2 @ W2T(batched) + bo   (fp32 out, K=128, 256 blocks)
  gemm2_256<<<256, 512, 0, stream>>>(P2, W2T, out, bo);
}

// Round 8
// 295.336 us; speedup vs baseline: 1.1082x; 1.0473x over previous
//
#include <hip/hip_runtime.h>
#include <hip/hip_bf16.h>
#include <stdint.h>

typedef __bf16 bf16;
typedef __attribute__((ext_vector_type(8))) __bf16 bf16x8;
typedef __attribute__((ext_vector_type(4))) float f32x4;
typedef __attribute__((ext_vector_type(4))) unsigned int u32x4;

#define NH 16
#define DH 64
#define POOL 8
#define BATCH 4
#define SEQ 4096
#define DIMV 1024
#define QKV_N (3*DIMV)
#define M_TOTAL (BATCH*SEQ)
#define SCALE_F 0.125f
// agent buffer holds SUMS over 512 t (from GEMM1-epilogue atomics);
// consumers fold mean (1/512) into the pre-softmax dot: exact.
#define AGS_F (SCALE_F / 512.0f)
#define BH (BATCH*NH)              // 64
#define QKVSZ ((size_t)BH*SEQ*DH)  // elems per q/k/v plane
#define TCH 16                     // t-split chunks for stage1
#define TCL (SEQ/TCH)              // 256 t per chunk
#define HP 128                     // h*p combined dim for P2/W2

#define AS1(p) ((const __attribute__((address_space(1))) void*)(p))
#define AS3(p) ((__attribute__((address_space(3))) void*)(p))
typedef const __attribute__((address_space(3))) char* lds_cp;

// ---------------- fused prep: x->bf16 convert + both weight transposes ------
// block ranges: [0,8192) convert_x; [8192,11264) Wqkv transpose; rest Wo.
__global__ void prep(const float* __restrict__ x, bf16* __restrict__ xb,
                     const float* __restrict__ Wqkv, bf16* __restrict__ WqkvT,
                     const float* __restrict__ Wo, bf16* __restrict__ WoT) {
  __shared__ float tile[32][33];
  const int b = blockIdx.x;
  if (b < 8192) {
    size_t i = ((size_t)b * 256 + threadIdx.x) * 8;
    float4 f0 = *(const float4*)(x + i);
    float4 f1 = *(const float4*)(x + i + 4);
    bf16x8 o;
    o[0] = (bf16)f0.x; o[1] = (bf16)f0.y; o[2] = (bf16)f0.z; o[3] = (bf16)f0.w;
    o[4] = (bf16)f1.x; o[5] = (bf16)f1.y; o[6] = (bf16)f1.z; o[7] = (bf16)f1.w;
    *(bf16x8*)(xb + i) = o;
    return;
  }
  const float* in; bf16* out; int C, bx, by;
  if (b < 8192 + 3072) { int bb = b - 8192;  in = Wqkv; out = WqkvT; C = QKV_N; bx = bb % 96; by = bb / 96; }
  else                 { int bb = b - 11264; in = Wo;   out = WoT;   C = DIMV;  bx = bb % 32; by = bb / 32; }
  const int R = DIMV;
  int c0 = bx * 32, r0 = by * 32;
  int tx = threadIdx.x & 31, ty = threadIdx.x >> 5;
  for (int i = ty; i < 32; i += 8)
    tile[i][tx] = in[(size_t)(r0 + i) * C + c0 + tx];
  __syncthreads();
  for (int i = ty; i < 32; i += 8)
    out[(size_t)(c0 + i) * R + r0 + tx] = (bf16)tile[tx][i];
}

// ============================================================================
// GEMM1: 256x256 tile, BK=64, 8 waves, 8-phase schedule (R1-verified).
// R8 delta: m201's optional lgkmcnt(8) before BAR#1 in the 12-read phases
// (smooths LDS drain across the barrier; waves reach the MFMA cluster
// together).  Everything else byte-identical to R1 (106.5us, 41% MfmaUtil,
// 0 bank conflicts).  1 block/CU is structural (128 acc VGPR/thread).
// ============================================================================
__global__ __launch_bounds__(512, 2)
void gemm1_qkv(const bf16* __restrict__ A, const bf16* __restrict__ B,
               bf16* __restrict__ qkvOut, float* __restrict__ agentSum) {
  constexpr int K1 = DIMV;       // 1024
  constexpr int NI = K1 / 128;   // 8 pipeline iterations (2 K-tiles each)

  __shared__ __align__(16) bf16 LA[2][2][8192];   // [buf][half][128*64]
  __shared__ __align__(16) bf16 LB[2][2][8192];

  const int tid  = threadIdx.x;
  const int w    = tid >> 6;
  const int lane = tid & 63;
  const int wm = (w >> 2) * 128;         // 2 M-waves x 4 N-waves
  const int wn = (w & 3) * 64;

  // bijective XCD swizzle (768 % 8 == 0)
  const int bid = blockIdx.x;
  const int swz = (bid & 7) * 96 + (bid >> 3);
  const int m0 = (swz / 12) * 256;
  const int n0 = (swz % 12) * 256;

  // staging: thread t covers (row rT + 64*e + 128*half, 16B slot t&7);
  // source column pre-swizzled so linear LDS dest realizes slot^(row&7).
  const int rT  = tid >> 3;
  const int csT = (((tid & 7) ^ (rT & 7)) << 3);
  const bf16* Ag = A + (size_t)(m0 + rT) * K1 + csT;
  const bf16* Bg = B + (size_t)(n0 + rT) * K1 + csT;

  // ds_read lane constants: row rA within 16-row frag, k-group C, xor rA&7
  const int rA = lane & 15, C = lane >> 4, xr = rA & 7;
  const unsigned s0 = (unsigned)(((0 * 4 + C) ^ xr) << 4);   // ks=0 slot byte
  const unsigned s1 = (unsigned)(((1 * 4 + C) ^ xr) << 4);   // ks=1 slot byte
  const unsigned aoff = (unsigned)((wm + rA) << 7);          // folds half+row
  const unsigned boff = (unsigned)((wn + rA) << 7);

  f32x4 acc[8][4] = {};
  u32x4 aR[4][2], bR[4][2];

#define STG(arr, Gp, half, kofs) do {                                         \
    const bf16* _s = (Gp) + (size_t)((half) * 128) * K1 + (kofs);             \
    char* _d = (char*)&arr[half][0] + (w << 10);                              \
    __builtin_amdgcn_global_load_lds(AS1(_s), AS3(_d), 16, 0, 0);             \
    __builtin_amdgcn_global_load_lds(AS1(_s + 64 * K1), AS3(_d + 8192), 16, 0, 0); \
  } while (0)

#define DSR0(d, p)    asm volatile("ds_read_b128 %0, %1" : "=v"(d) : "v"(p))
#define DSR(d, p, o)  asm volatile("ds_read_b128 %0, %1 offset:" o : "=v"(d) : "v"(p))

#define READS_A(LAb, qm) do {                                                 \
    lds_cp _p0 = (lds_cp)(const char*)&LAb[0][0] + aoff + s0 + (qm) * 8192;   \
    lds_cp _p1 = (lds_cp)(const char*)&LAb[0][0] + aoff + s1 + (qm) * 8192;   \
    DSR0(aR[0][0], _p0); DSR(aR[1][0], _p0, "2048");                          \
    DSR(aR[2][0], _p0, "4096"); DSR(aR[3][0], _p0, "6144");                   \
    DSR0(aR[0][1], _p1); DSR(aR[1][1], _p1, "2048");                          \
    DSR(aR[2][1], _p1, "4096"); DSR(aR[3][1], _p1, "6144");                   \
  } while (0)

#define READS_B01(LBb) do {                                                   \
    lds_cp _p0 = (lds_cp)(const char*)&LBb[0][0] + boff + s0;                 \
    lds_cp _p1 = (lds_cp)(const char*)&LBb[0][0] + boff + s1;                 \
    DSR0(bR[0][0], _p0); DSR(bR[1][0], _p0, "2048");                          \
    DSR0(bR[0][1], _p1); DSR(bR[1][1], _p1, "2048");                          \
  } while (0)

#define READS_B23(LBb) do {                                                   \
    lds_cp _p0 = (lds_cp)(const char*)&LBb[0][0] + boff + s0;                 \
    lds_cp _p1 = (lds_cp)(const char*)&LBb[0][0] + boff + s1;                 \
    DSR(bR[2][0], _p0, "4096"); DSR(bR[3][0], _p0, "6144");                   \
    DSR(bR[2][1], _p1, "4096"); DSR(bR[3][1], _p1, "6144");                   \
  } while (0)

// m201 optional smoothing wait for 12-read phases (rule #18: sched_barrier)
#define WAITL8 do { asm volatile("s_waitcnt lgkmcnt(8)");                     \
                    __builtin_amdgcn_sched_barrier(0); } while (0)

#define MFMA_Q(qm, qn) do {                                                   \
    asm volatile("s_waitcnt lgkmcnt(0)");                                     \
    __builtin_amdgcn_sched_barrier(0);                                        \
    __builtin_amdgcn_s_setprio(1);                                            \
    _Pragma("unroll")                                                         \
    for (int il = 0; il < 4; ++il)                                            \
      _Pragma("unroll")                                                       \
      for (int jj = 0; jj < 2; ++jj) {                                        \
        f32x4& ac = acc[(qm) * 4 + il][(qn) * 2 + jj];                        \
        ac = __builtin_amdgcn_mfma_f32_16x16x32_bf16(                         \
            __builtin_bit_cast(bf16x8, aR[il][0]),                            \
            __builtin_bit_cast(bf16x8, bR[(qn) * 2 + jj][0]), ac, 0, 0, 0);   \
        ac = __builtin_amdgcn_mfma_f32_16x16x32_bf16(                         \
            __builtin_bit_cast(bf16x8, aR[il][1]),                            \
            __builtin_bit_cast(bf16x8, bR[(qn) * 2 + jj][1]), ac, 0, 0, 0);   \
      }                                                                       \
    __builtin_amdgcn_s_setprio(0);                                            \
    __builtin_amdgcn_sched_barrier(0);                                        \
  } while (0)

#define BAR __builtin_amdgcn_s_barrier()

  // prologue: tile0 (A+B) -> buf0; tile1 B -> buf1   (12 issues)
  STG(LA[0], Ag, 0, 0); STG(LA[0], Ag, 1, 0);
  STG(LB[0], Bg, 0, 0); STG(LB[0], Bg, 1, 0);
  STG(LB[1], Bg, 0, 64); STG(LB[1], Bg, 1, 64);
  asm volatile("s_waitcnt vmcnt(4)");    // buf0 tile landed; buf1 B in flight
  __builtin_amdgcn_sched_barrier(0);
  BAR;

  int kk = 0;
  for (int i = 0; i < NI - 1; ++i, kk += 128) {
    // ---- phases 1-4: consume buf0 (tile 2i) ----
    READS_A(LA[0], 0); READS_B01(LB[0]);
    STG(LA[1], Ag, 0, kk + 64);          // ph1: buf1.A0 <- tile 2i+1
    WAITL8;                              // 12-read phase: smooth LDS drain
    BAR; MFMA_Q(0, 0); BAR;
    READS_B23(LB[0]);
    STG(LA[1], Ag, 1, kk + 64);          // ph2: buf1.A1 <- tile 2i+1
    BAR; MFMA_Q(0, 1); BAR;
    READS_A(LA[0], 1);
    STG(LB[0], Bg, 0, kk + 128);         // ph3: buf0.B0 <- tile 2i+2
    BAR; MFMA_Q(1, 0); BAR;
    STG(LB[0], Bg, 1, kk + 128);         // ph4: buf0.B1 <- tile 2i+2
    BAR; MFMA_Q(1, 1);
    asm volatile("s_waitcnt vmcnt(4)");  // buf1 tile 2i+1 landed
    __builtin_amdgcn_sched_barrier(0);
    BAR;
    // ---- phases 5-8: consume buf1 (tile 2i+1) ----
    READS_A(LA[1], 0); READS_B01(LB[1]);
    STG(LA[0], Ag, 0, kk + 128);         // ph5: buf0.A0 <- tile 2i+2
    WAITL8;                              // 12-read phase
    BAR; MFMA_Q(0, 0); BAR;
    READS_B23(LB[1]);
    STG(LA[0], Ag, 1, kk + 128);         // ph6: buf0.A1 <- tile 2i+2
    BAR; MFMA_Q(0, 1); BAR;
    READS_A(LA[1], 1);
    STG(LB[1], Bg, 0, kk + 192);         // ph7: buf1.B0 <- tile 2i+3
    BAR; MFMA_Q(1, 0); BAR;
    STG(LB[1], Bg, 1, kk + 192);         // ph8: buf1.B1 <- tile 2i+3
    BAR; MFMA_Q(1, 1);
    asm volatile("s_waitcnt vmcnt(4)");  // buf0 tile 2i+2 landed
    __builtin_amdgcn_sched_barrier(0);
    BAR;
  }
  // ---- tail iteration: buf0 = tile NT-2, buf1 = tile NT-1 ----
  READS_A(LA[0], 0); READS_B01(LB[0]);
  STG(LA[1], Ag, 0, kk + 64);            // last A halves of tile NT-1
  WAITL8;
  BAR; MFMA_Q(0, 0); BAR;
  READS_B23(LB[0]);
  STG(LA[1], Ag, 1, kk + 64);
  BAR; MFMA_Q(0, 1); BAR;
  READS_A(LA[0], 1);
  BAR; MFMA_Q(1, 0); BAR;
  MFMA_Q(1, 1);
  asm volatile("s_waitcnt vmcnt(0)");    // drain: buf1 tile NT-1 landed
  __builtin_amdgcn_sched_barrier(0);
  BAR;
  READS_A(LA[1], 0); READS_B01(LB[1]);
  WAITL8;
  BAR; MFMA_Q(0, 0); BAR;
  READS_B23(LB[1]);
  BAR; MFMA_Q(0, 1); BAR;
  READS_A(LA[1], 1);
  BAR; MFMA_Q(1, 0); BAR;
  MFMA_Q(1, 1);

#undef STG
#undef DSR0
#undef DSR
#undef READS_A
#undef READS_B01
#undef READS_B23
#undef WAITL8
#undef MFMA_Q
#undef BAR

  // ---- epilogue: scatter to q/k/v planes (C/D layout col=lane&15,
  //      row=(lane>>4)*4+r); wave owns rows [m0+wm,+128), cols = one 64-d head.
  const int cr = (lane >> 4) * 4;
  const int cc = lane & 15;
  const int ncol  = n0 + wn;             // multiple of 64 -> single (plane,head)
  const int which = ncol >> 10;
  const int hh    = (ncol >> 6) & 15;
  const int rowb  = m0 + wm;
  const int bb_   = rowb >> 12;
  const int tb    = rowb & 4095;
  bf16* Cp = qkvOut + (size_t)which * QKVSZ + (size_t)(bb_ * NH + hh) * SEQ * DH;
#pragma unroll
  for (int i = 0; i < 8; ++i)
#pragma unroll
    for (int j = 0; j < 4; ++j)
#pragma unroll
      for (int r = 0; r < 4; ++r)
        Cp[(size_t)(tb + i * 16 + cr + r) * DH + j * 16 + cc] = (bf16)acc[i][j][r];

  // fused agent pooling (q plane only): all 128 rows lie in one 512-t bucket.
  if (which == 0) {
    const int pp = tb >> 9;
    float* ag = agentSum + ((size_t)(bb_ * NH + hh) * POOL + pp) * DH;
#pragma unroll
    for (int j = 0; j < 4; ++j) {
      float s = 0.f;
#pragma unroll
      for (int i = 0; i < 8; ++i)
        s += acc[i][j][0] + acc[i][j][1] + acc[i][j][2] + acc[i][j][3];
      s += __shfl_xor(s, 16);
      s += __shfl_xor(s, 32);
      if (lane < 16) atomicAdd(&ag[j * 16 + lane], s);
    }
  }
}

// ============================================================================
// GEMM2: out = P2 @ W2T(batched)^T + bo.  256x256 tile, K=128 (2 K-tiles,
// R1-verified prologue+tail path).  Grid 256 = 1 block/CU.
// ============================================================================
__global__ __launch_bounds__(512, 2)
void gemm2_256(const bf16* __restrict__ A, const bf16* __restrict__ B,
               float* __restrict__ Out, const float* __restrict__ bias) {
  constexpr int K2 = HP;   // 128

  __shared__ __align__(16) bf16 LA[2][2][8192];
  __shared__ __align__(16) bf16 LB[2][2][8192];

  const int tid  = threadIdx.x;
  const int w    = tid >> 6;
  const int lane = tid & 63;
  const int wm = (w >> 2) * 128;
  const int wn = (w & 3) * 64;

  const int bid = blockIdx.x;
  const int swz = (bid & 7) * 32 + (bid >> 3);   // bijective, 256 % 8 == 0
  const int m0 = (swz >> 2) * 256;
  const int n0 = (swz & 3) * 256;

  const int rT  = tid >> 3;
  const int csT = (((tid & 7) ^ (rT & 7)) << 3);
  const bf16* Ag = A + (size_t)(m0 + rT) * K2 + csT;
  // B = W2T [batch][n][hp]; 256 | 4096 -> whole M-tile in one batch
  const bf16* Bg = B + ((size_t)(m0 >> 12) * DIMV + n0 + rT) * K2 + csT;

  const int rA = lane & 15, C = lane >> 4, xr = rA & 7;
  const unsigned s0 = (unsigned)(((0 * 4 + C) ^ xr) << 4);
  const unsigned s1 = (unsigned)(((1 * 4 + C) ^ xr) << 4);
  const unsigned aoff = (unsigned)((wm + rA) << 7);
  const unsigned boff = (unsigned)((wn + rA) << 7);

  f32x4 acc[8][4] = {};
  u32x4 aR[4][2], bR[4][2];

#define STG(arr, Gp, half, kofs) do {                                         \
    const bf16* _s = (Gp) + (size_t)((half) * 128) * K2 + (kofs);             \
    char* _d = (char*)&arr[half][0] + (w << 10);                              \
    __builtin_amdgcn_global_load_lds(AS1(_s), AS3(_d), 16, 0, 0);             \
    __builtin_amdgcn_global_load_lds(AS1(_s + 64 * K2), AS3(_d + 8192), 16, 0, 0); \
  } while (0)

#define DSR0(d, p)    asm volatile("ds_read_b128 %0, %1" : "=v"(d) : "v"(p))
#define DSR(d, p, o)  asm volatile("ds_read_b128 %0, %1 offset:" o : "=v"(d) : "v"(p))

#define READS_A(LAb, qm) do {                                                 \
    lds_cp _p0 = (lds_cp)(const char*)&LAb[0][0] + aoff + s0 + (qm) * 8192;   \
    lds_cp _p1 = (lds_cp)(const char*)&LAb[0][0] + aoff + s1 + (qm) * 8192;   \
    DSR0(aR[0][0], _p0); DSR(aR[1][0], _p0, "2048");                          \
    DSR(aR[2][0], _p0, "4096"); DSR(aR[3][0], _p0, "6144");                   \
    DSR0(aR[0][1], _p1); DSR(aR[1][1], _p1, "2048");                          \
    DSR(aR[2][1], _p1, "4096"); DSR(aR[3][1], _p1, "6144");                   \
  } while (0)

#define READS_B01(LBb) do {                                                   \
    lds_cp _p0 = (lds_cp)(const char*)&LBb[0][0] + boff + s0;                 \
    lds_cp _p1 = (lds_cp)(const char*)&LBb[0][0] + boff + s1;                 \
    DSR0(bR[0][0], _p0); DSR(bR[1][0], _p0, "2048");                          \
    DSR0(bR[0][1], _p1); DSR(bR[1][1], _p1, "2048");                          \
  } while (0)

#define READS_B23(LBb) do {                                                   \
    lds_cp _p0 = (lds_cp)(const char*)&LBb[0][0] + boff + s0;                 \
    lds_cp _p1 = (lds_cp)(const char*)&LBb[0][0] + boff + s1;                 \
    DSR(bR[2][0], _p0, "4096"); DSR(bR[3][0], _p0, "6144");                   \
    DSR(bR[2][1], _p1, "4096"); DSR(bR[3][1], _p1, "6144");                   \
  } while (0)

#define WAITL8 do { asm volatile("s_waitcnt lgkmcnt(8)");                     \
                    __builtin_amdgcn_sched_barrier(0); } while (0)

#define MFMA_Q(qm, qn) do {                                                   \
    asm volatile("s_waitcnt lgkmcnt(0)");                                     \
    __builtin_amdgcn_sched_barrier(0);                                        \
    __builtin_amdgcn_s_setprio(1);                                            \
    _Pragma("unroll")                                                         \
    for (int il = 0; il < 4; ++il)                                            \
      _Pragma("unroll")                                                       \
      for (int jj = 0; jj < 2; ++jj) {                                        \
        f32x4& ac = acc[(qm) * 4 + il][(qn) * 2 + jj];                        \
        ac = __builtin_amdgcn_mfma_f32_16x16x32_bf16(                         \
            __builtin_bit_cast(bf16x8, aR[il][0]),                            \
            __builtin_bit_cast(bf16x8, bR[(qn) * 2 + jj][0]), ac, 0, 0, 0);   \
        ac = __builtin_amdgcn_mfma_f32_16x16x32_bf16(                         \
            __builtin_bit_cast(bf16x8, aR[il][1]),                            \
            __builtin_bit_cast(bf16x8, bR[(qn) * 2 + jj][1]), ac, 0, 0, 0);   \
      }                                                                       \
    __builtin_amdgcn_s_setprio(0);                                            \
    __builtin_amdgcn_sched_barrier(0);                                        \
  } while (0)

#define BAR __builtin_amdgcn_s_barrier()

  // prologue (R1 pattern): tile0 A+B -> buf0; tile1 B -> buf1
  STG(LA[0], Ag, 0, 0); STG(LA[0], Ag, 1, 0);
  STG(LB[0], Bg, 0, 0); STG(LB[0], Bg, 1, 0);
  STG(LB[1], Bg, 0, 64); STG(LB[1], Bg, 1, 64);
  asm volatile("s_waitcnt vmcnt(4)");
  __builtin_amdgcn_sched_barrier(0);
  BAR;

  // tile 0 (R1 tail structure, kk = 0)
  READS_A(LA[0], 0); READS_B01(LB[0]);
  STG(LA[1], Ag, 0, 64);
  WAITL8;
  BAR; MFMA_Q(0, 0); BAR;
  READS_B23(LB[0]);
  STG(LA[1], Ag, 1, 64);
  BAR; MFMA_Q(0, 1); BAR;
  READS_A(LA[0], 1);
  BAR; MFMA_Q(1, 0); BAR;
  MFMA_Q(1, 1);
  asm volatile("s_waitcnt vmcnt(0)");
  __builtin_amdgcn_sched_barrier(0);
  BAR;
  // tile 1
  READS_A(LA[1], 0); READS_B01(LB[1]);
  WAITL8;
  BAR; MFMA_Q(0, 0); BAR;
  READS_B23(LB[1]);
  BAR; MFMA_Q(0, 1); BAR;
  READS_A(LA[1], 1);
  BAR; MFMA_Q(1, 0); BAR;
  MFMA_Q(1, 1);

#undef STG
#undef DSR0
#undef DSR
#undef READS_A
#undef READS_B01
#undef READS_B23
#undef WAITL8
#undef MFMA_Q
#undef BAR

  // epilogue: fp32 row-major + bias
  const int cr = (lane >> 4) * 4;
  const int cc = lane & 15;
  const int rowb = m0 + wm;
  float bb4[4];
#pragma unroll
  for (int j = 0; j < 4; ++j) bb4[j] = bias[n0 + wn + j * 16 + cc];
#pragma unroll
  for (int i = 0; i < 8; ++i)
#pragma unroll
    for (int j = 0; j < 4; ++j) {
      const int col = n0 + wn + j * 16 + cc;
#pragma unroll
      for (int r = 0; r < 4; ++r)
        Out[(size_t)(rowb + i * 16 + cr + r) * DIMV + col] = acc[i][j][r] + bb4[j];
    }
}

// ============================================================================
// attn_mid: fused p2_build + stage1 (R7-verified, +8us net).  R8 delta:
// hoist full q/k row loads (8x16B each) ahead of the dot loop -- each 128B
// line is fetched once while resident instead of re-touched across 8
// spread-out dc iterations (64KB/block working set vs 32KB L1 -> ~50% miss
// in the R7 layout).  +32 VGPR, occupancy grid-limited (4 blocks/CU) anyway.
// ============================================================================
__global__ __launch_bounds__(256)
void attn_mid(const bf16* __restrict__ q, const bf16* __restrict__ k,
              const bf16* __restrict__ v, const float* __restrict__ agentSum,
              bf16* __restrict__ P2,
              float* __restrict__ pm, float* __restrict__ pl,
              float* __restrict__ pva) {
  const int tc = blockIdx.x, bh = blockIdx.y;
  const int tid = threadIdx.x;
  const int t0 = tc * TCL;

  __shared__ float agT[64][8];           // [d][p], scaled by SCALE/512
  __shared__ float se[TCL][9];           // exp(sck-m), pad to 9
  __shared__ float rm[4][8], rl[4][8];

  for (int i = tid; i < 512; i += 256) {
    int p = i >> 6, d = i & 63;
    agT[d][p] = agentSum[(size_t)bh * 512 + i] * AGS_F;
  }
  __syncthreads();

  // ---- phase 1: q-row and k-row share the agT read stream ----
  const bf16* qrow = q + ((size_t)bh * SEQ + t0 + tid) * DH;
  const bf16* krow = k + ((size_t)bh * SEQ + t0 + tid) * DH;
  bf16x8 qv8[8], kv8[8];
#pragma unroll
  for (int dc = 0; dc < 8; ++dc) {
    qv8[dc] = *(const bf16x8*)(qrow + dc * 8);
    kv8[dc] = *(const bf16x8*)(krow + dc * 8);
  }
  float scq[8] = {}, sck[8] = {};
#pragma unroll
  for (int dc = 0; dc < 8; ++dc) {
#pragma unroll
    for (int e = 0; e < 8; ++e) {
      float qv = (float)qv8[dc][e];
      float kv = (float)kv8[dc][e];
      int d = dc * 8 + e;
      float4 a0 = *(const float4*)&agT[d][0];
      float4 a1 = *(const float4*)&agT[d][4];
      scq[0] += a0.x * qv; scq[1] += a0.y * qv; scq[2] += a0.z * qv; scq[3] += a0.w * qv;
      scq[4] += a1.x * qv; scq[5] += a1.y * qv; scq[6] += a1.z * qv; scq[7] += a1.w * qv;
      sck[0] += a0.x * kv; sck[1] += a0.y * kv; sck[2] += a0.z * kv; sck[3] += a0.w * kv;
      sck[4] += a1.x * kv; sck[5] += a1.y * kv; sck[6] += a1.z * kv; sck[7] += a1.w * kv;
    }
  }

  // P2: per-row softmax over p (independent of k path)
  {
    float m = scq[0];
#pragma unroll
    for (int p = 1; p < 8; ++p) m = fmaxf(m, scq[p]);
    float wsum = 0.f, wgt[8];
#pragma unroll
    for (int p = 0; p < 8; ++p) { wgt[p] = __expf(scq[p] - m); wsum += wgt[p]; }
    float inv = 1.0f / wsum;
    int b = bh >> 4, h = bh & 15;
    bf16x8 o8;
#pragma unroll
    for (int p = 0; p < 8; ++p) o8[p] = (bf16)(wgt[p] * inv);
    *(bf16x8*)&P2[((size_t)(b * SEQ + t0 + tid)) * HP + h * 8] = o8;
  }

  // k path: chunk max
  float mx[8];
#pragma unroll
  for (int p = 0; p < 8; ++p) mx[p] = sck[p];
#pragma unroll
  for (int o = 32; o; o >>= 1)
#pragma unroll
    for (int p = 0; p < 8; ++p) mx[p] = fmaxf(mx[p], __shfl_xor(mx[p], o));
  if ((tid & 63) == 0)
#pragma unroll
    for (int p = 0; p < 8; ++p) rm[tid >> 6][p] = mx[p];
  __syncthreads();
  float m[8];
#pragma unroll
  for (int p = 0; p < 8; ++p)
    m[p] = fmaxf(fmaxf(rm[0][p], rm[1][p]), fmaxf(rm[2][p], rm[3][p]));

  float sl[8];
#pragma unroll
  for (int p = 0; p < 8; ++p) {
    float e = __expf(sck[p] - m[p]);
    se[tid][p] = e;
    sl[p] = e;
  }
#pragma unroll
  for (int o = 32; o; o >>= 1)
#pragma unroll
    for (int p = 0; p < 8; ++p) sl[p] += __shfl_xor(sl[p], o);
  if ((tid & 63) == 0)
#pragma unroll
    for (int p = 0; p < 8; ++p) rl[tid >> 6][p] = sl[p];
  __syncthreads();
  if (tid < 8) {
    float l = rl[0][tid] + rl[1][tid] + rl[2][tid] + rl[3][tid];
    pm[(size_t)(bh * TCH + tc) * 8 + tid] = m[tid];
    pl[(size_t)(bh * TCH + tc) * 8 + tid] = l;
  }
  __syncthreads();   // se complete for phase 2

  // ---- phase 2: pva[p][d] = sum_t se[t][p]*v[t][d] ----
  const int lane = tid & 63;
  const int wv = tid >> 6;          // wave id: p = {2wv, 2wv+1}
  const int dg = lane & 7;          // d-octet
  const int to = lane >> 3;         // 0..7 t-offset (full range in-wave)
  const int p0 = wv * 2;
  const bf16* vb = v + ((size_t)bh * SEQ + t0 + to) * DH + dg * 8;
  float a0[8] = {}, a1[8] = {};
  for (int tl = to; tl < TCL; tl += 8) {
    bf16x8 v8 = *(const bf16x8*)(vb + (size_t)(tl - to) * DH);
    float w0 = se[tl][p0];
    float w1 = se[tl][p0 + 1];
#pragma unroll
    for (int e = 0; e < 8; ++e) {
      float vf = (float)v8[e];
      a0[e] += w0 * vf;
      a1[e] += w1 * vf;
    }
  }
  // reduce over to (lane bits 3,4,5)
#pragma unroll
  for (int o = 8; o <= 32; o <<= 1) {
#pragma unroll
    for (int e = 0; e < 8; ++e) {
      a0[e] += __shfl_xor(a0[e], o);
      a1[e] += __shfl_xor(a1[e], o);
    }
  }
  if (to == 0) {   // lanes 0..7 hold sums
    float* o0 = pva + ((size_t)(bh * TCH + tc) * 8 + p0) * DH + dg * 8;
    float* o1 = o0 + DH;
#pragma unroll
    for (int e = 0; e < 8; ++e) { o0[e] = a0[e]; o1[e] = a1[e]; }
  }
}

// ---------------- combine chunk partials -> v_agent[bh][p][d] ----------------
__global__ void combine_vag(const float* __restrict__ pm, const float* __restrict__ pl,
                            const float* __restrict__ pva, float* __restrict__ vag) {
  int bh = blockIdx.x;
#pragma unroll
  for (int e = threadIdx.x; e < 512; e += 256) {
    int p = e >> 6, d = e & 63;
    float M = -1e30f;
#pragma unroll
    for (int tc = 0; tc < TCH; ++tc)
      M = fmaxf(M, pm[(size_t)(bh * TCH + tc) * 8 + p]);
    float L = 0.f, acc = 0.f;
#pragma unroll
    for (int tc = 0; tc < TCH; ++tc) {
      float w = __expf(pm[(size_t)(bh * TCH + tc) * 8 + p] - M);
      L   += w * pl[(size_t)(bh * TCH + tc) * 8 + p];
      acc += w * pva[((size_t)(bh * TCH + tc) * 8 + p) * DH + d];
    }
    vag[(size_t)bh * 512 + e] = acc / L;
  }
}

// ---- W2T[b][n][hp] = sum_d vag[b][hp][d] * WoT[n][h*64+d]  (bf16 out) ----
__global__ void w2_build(const float* __restrict__ vag, const bf16* __restrict__ WoT,
                         bf16* __restrict__ W2T) {
  int b = blockIdx.y;
  int n = blockIdx.x * 16 + (threadIdx.x & 15);
  int h = threadIdx.x >> 4;
  __shared__ float vg[128][65];
  for (int i = threadIdx.x; i < 128 * 64; i += 256)
    vg[i >> 6][i & 63] = vag[(size_t)b * 128 * 64 + i];
  __syncthreads();
  float acc[8] = {};
  const bf16* wrow = WoT + (size_t)n * DIMV + h * 64;
#pragma unroll
  for (int dv = 0; dv < 8; ++dv) {
    bf16x8 wv = *(const bf16x8*)(wrow + dv * 8);
#pragma unroll
    for (int e = 0; e < 8; ++e) {
      float wf = (float)wv[e];
      int d = dv * 8 + e;
#pragma unroll
      for (int p = 0; p < 8; ++p) acc[p] += vg[h * 8 + p][d] * wf;
    }
  }
  bf16x8 o;
#pragma unroll
  for (int p = 0; p < 8; ++p) o[p] = (bf16)acc[p];
  *(bf16x8*)&W2T[((size_t)b * DIMV + n) * HP + h * 8] = o;
}

extern "C" void kernel_launch(void* const* d_in, const int* in_sizes, int n_in,
                              void* d_out, int out_size, void* d_ws, size_t ws_size,
                              hipStream_t stream) {
  const float* x    = (const float*)d_in[0];   // [4,4096,1024] fp32
  const float* Wqkv = (const float*)d_in[1];   // [1024,3072]   fp32
  const float* Wo   = (const float*)d_in[2];   // [1024,1024]   fp32
  const float* bo   = (const float*)d_in[3];   // [1024]        fp32
  float* out = (float*)d_out;                  // [4,4096,1024] fp32

  char* ws = (char*)d_ws;
  bf16* WqkvT = (bf16*)ws;                                   ws += (size_t)QKV_N * DIMV * 2;
  bf16* WoT   = (bf16*)ws;                                   ws += (size_t)DIMV * DIMV * 2;
  bf16* qkv   = (bf16*)ws;                                   ws += 3 * QKVSZ * 2;
  char* wsu   = ws;                                          ws += (size_t)M_TOTAL * DIMV * 2;
  bf16*  xb    = (bf16*)wsu;
  bf16*  P2    = (bf16*)wsu;                                  // 4 MB (after xb dead)
  bf16*  W2T   = (bf16*)(wsu + (size_t)M_TOTAL * HP * 2);     // 1 MB
  float* agent = (float*)ws;                                 ws += 512 * 64 * 4;
  float* pm    = (float*)ws;                                 ws += BH * TCH * 8 * 4;
  float* pl    = (float*)ws;                                 ws += BH * TCH * 8 * 4;
  float* pva   = (float*)ws;                                 ws += (size_t)BH * TCH * 8 * DH * 4;
  float* vag   = (float*)ws;                                 ws += 512 * 64 * 4;

  const bf16* qp = qkv;
  const bf16* kp = qkv + QKVSZ;
  const bf16* vp = qkv + 2 * QKVSZ;

  // agent accumulated by GEMM1-epilogue atomics -> zero it first
  hipMemsetAsync(agent, 0, 512 * 64 * 4, stream);

  // fused prep: convert_x (8192 blocks) + Wqkv transpose (3072) + Wo (1024)
  prep<<<12288, 256, 0, stream>>>(x, xb, Wqkv, WqkvT, Wo, WoT);

  // GEMM1: qkv = x @ Wqkv (split planes) + fused q pooling sums
  gemm1_qkv<<<768, 512, 0, stream>>>(xb, WqkvT, qkv, agent);

  // fused p2_build + stage1
  attn_mid<<<dim3(TCH, BH), 256, 0, stream>>>(qp, kp, vp, agent, P2, pm, pl, pva);

  combine_vag<<<BH, 256, 0, stream>>>(pm, pl, pva, vag);
  w2_build<<<dim3(DIMV / 16, BATCH), 256, 0, stream>>>(vag, WoT, W2T);

  // GEMM2: out = P2 @ W2T(batched) + bo   (fp32 out, K=128, 256 blocks)
  gemm2_256<<<256, 512, 0, stream>>>(P2, W2T, out, bo);
}